// Round 2
// baseline (422.410 us; speedup 1.0000x reference)
//
#include <hip/hip_runtime.h>
#include <hip/hip_bf16.h>

#define NFR 8
#define CDIM 128
#define NH 8
#define HD 16
#define HH 96
#define WWIDTH 96
#define NB 4
#define PIX 8
#define MROWS 64         // PIX*NFR token rows per block
#define HWSZ 9216        // HH*WWIDTH
#define XSTR 132         // CDIM + 4 pad (bf16 elems)

typedef __attribute__((ext_vector_type(8))) short bf16x8;
typedef __attribute__((ext_vector_type(4))) float f32x4;

union FragU { uint4 u; bf16x8 v; };

__device__ inline float bf2f(unsigned short h) {
    unsigned int x = ((unsigned int)h) << 16;
    float f;
    __builtin_memcpy(&f, &x, 4);
    return f;
}
__device__ inline unsigned short f2bf(float f) {
    unsigned int x;
    __builtin_memcpy(&x, &f, 4);
    return (unsigned short)((x + 0x7FFFu + ((x >> 16) & 1u)) >> 16);
}

// LDS scratch region byte offsets (union'd across phases)
#define OFF_BT    0        // Bt[48][XSTR] bf16 = 12672 B   (qkv weight slice, transposed)
#define OFF_QB    12672    // q[64][17] f32 = 4352 B
#define OFF_KB    17024    // k[64][17] f32
#define OFF_VB    21376    // v[64][17] f32
#define OFF_PR    25728    // probs[64][8] f32 = 2048 B
#define SCRATCH_B 27776
// proj phase reuses offset 0: Btp[128][68] bf16 = 17408 B (aliases Bt/qb/kb head-phase bufs)

__global__ __launch_bounds__(256)
void cfa_fused(const float* __restrict__ feat,
               const float* __restrict__ wqkv,
               const float* __restrict__ wproj,
               const float* __restrict__ bproj,
               const float* __restrict__ gamma,
               const float* __restrict__ beta,
               float* __restrict__ outp)
{
    __shared__ __align__(16) unsigned short xln[MROWS][XSTR];   // 16896 B (reused as out_t in epilogue)
    __shared__ __align__(16) unsigned short attn[MROWS][XSTR];  // 16896 B
    __shared__ __align__(16) unsigned char scratch[SCRATCH_B];  // 27776 B  -> total 61568 B

    unsigned short* Bt    = (unsigned short*)(scratch + OFF_BT);
    float*          qb    = (float*)(scratch + OFF_QB);
    float*          kb    = (float*)(scratch + OFF_KB);
    float*          vb    = (float*)(scratch + OFF_VB);
    float*          probs = (float*)(scratch + OFF_PR);
    unsigned short* Btp   = (unsigned short*)(scratch + OFF_BT);

    const int tid = threadIdx.x;
    const int blk = blockIdx.x;
    const int wt  = blk % (WWIDTH / PIX);            // 0..11
    const int h   = (blk / (WWIDTH / PIX)) % HH;     // 0..95
    const int b   = blk / ((WWIDTH / PIX) * HH);     // 0..3
    const int base = ((b * NFR) * CDIM) * HWSZ + h * WWIDTH + wt * PIX;

    // ---------------- load (f32 -> bf16) ----------------
    for (int it = 0; it < 4; ++it) {
        int u = it * 256 + tid;                      // u = n*128 + c, 0..1023
        const float* src = feat + base + u * HWSZ;   // 8 consecutive pixels
        float4 ra = *(const float4*)src;
        float4 rb = *(const float4*)(src + 4);
        int n = u >> 7, c = u & 127;
        xln[0 * NFR + n][c] = f2bf(ra.x);
        xln[1 * NFR + n][c] = f2bf(ra.y);
        xln[2 * NFR + n][c] = f2bf(ra.z);
        xln[3 * NFR + n][c] = f2bf(ra.w);
        xln[4 * NFR + n][c] = f2bf(rb.x);
        xln[5 * NFR + n][c] = f2bf(rb.y);
        xln[6 * NFR + n][c] = f2bf(rb.z);
        xln[7 * NFR + n][c] = f2bf(rb.w);
    }
    __syncthreads();
    // ---------------- LayerNorm (f32 math on bf16 values, in-place) ----------------
    {
        int row = tid >> 2;
        int seg = (tid & 3) * 32;
        float s = 0.f, ss = 0.f;
        #pragma unroll
        for (int e = 0; e < 32; ++e) {
            float x = bf2f(xln[row][seg + e]);
            s += x; ss += x * x;
        }
        s += __shfl_xor(s, 1); ss += __shfl_xor(ss, 1);
        s += __shfl_xor(s, 2); ss += __shfl_xor(ss, 2);
        float mu   = s * (1.f / 128.f);
        float var  = ss * (1.f / 128.f) - mu * mu;
        float rstd = rsqrtf(var + 1e-5f);
        #pragma unroll
        for (int e = 0; e < 32; ++e) {
            int c = seg + e;
            float x = bf2f(xln[row][c]);
            xln[row][c] = f2bf((x - mu) * rstd * gamma[c] + beta[c]);
        }
    }
    // LN->GEMM hazard covered by the post-staging barrier below.

    const int wv   = tid >> 6;      // wave id: M-tile owner (rows wv*16 .. wv*16+15)
    const int l    = tid & 63;
    const int lr   = l & 15;        // m/n fragment index
    const int lg   = l >> 4;        // k-group
    const int dgrp = tid & 3;

    // ---------------- per-head: qkv GEMM + attention ----------------
    for (int hd = 0; hd < NH; ++hd) {
        // stage Bt[s*16+cl][k] = bf16(wqkv[k][s*128 + hd*16 + cl])
        for (int it = 0; it < 12; ++it) {
            int u = it * 32 + (tid >> 3);            // 0..383
            int s = u >> 7, k = u & 127;
            int c2 = (tid & 7) * 2;
            float2 w2 = *(const float2*)(wqkv + k * 384 + s * 128 + hd * HD + c2);
            Bt[(s * 16 + c2) * XSTR + k]     = f2bf(w2.x);
            Bt[(s * 16 + c2 + 1) * XSTR + k] = f2bf(w2.y);
        }
        __syncthreads();   // staging done; also guarantees prev head's PV finished before q/k/v overwrite

        // qkv GEMM: 64x128 @ 128x48 (nt: 0=q, 1=k, 2=v)
        #pragma unroll
        for (int nt = 0; nt < 3; ++nt) {
            f32x4 acc = {0.f, 0.f, 0.f, 0.f};
            #pragma unroll
            for (int ks = 0; ks < 4; ++ks) {
                FragU a, bf;
                const unsigned short* pa = &xln[wv * 16 + lr][ks * 32 + lg * 4];
                uint2 alo = *(const uint2*)pa;
                uint2 ahi = *(const uint2*)(pa + 16);
                a.u.x = alo.x; a.u.y = alo.y; a.u.z = ahi.x; a.u.w = ahi.y;
                const unsigned short* pb = Bt + (nt * 16 + lr) * XSTR + ks * 32 + lg * 4;
                uint2 blo = *(const uint2*)pb;
                uint2 bhi = *(const uint2*)(pb + 16);
                bf.u.x = blo.x; bf.u.y = blo.y; bf.u.z = bhi.x; bf.u.w = bhi.y;
                acc = __builtin_amdgcn_mfma_f32_16x16x32_bf16(a.v, bf.v, acc, 0, 0, 0);
            }
            float* dst = (nt == 0) ? qb : ((nt == 1) ? kb : vb);
            #pragma unroll
            for (int j = 0; j < 4; ++j)
                dst[(wv * 16 + lg * 4 + j) * 17 + lr] = acc[j];
        }
        __syncthreads();

        // scores + softmax: 4 threads per token row, 2 keys each
        {
            int prow = tid >> 2;                 // token row 0..63
            int p8 = prow & ~7;                  // pixel base row
            int kj = dgrp * 2;
            const float* qrow = qb + prow * 17;
            const float* k0 = kb + (p8 + kj) * 17;
            const float* k1 = kb + (p8 + kj + 1) * 17;
            float s0 = 0.f, s1 = 0.f;
            #pragma unroll
            for (int dd = 0; dd < 16; ++dd) {
                float qv = qrow[dd];
                s0 += qv * k0[dd];
                s1 += qv * k1[dd];
            }
            s0 *= 0.25f; s1 *= 0.25f;            // SCALE = 16^-0.5
            float mx = fmaxf(s0, s1);
            mx = fmaxf(mx, __shfl_xor(mx, 1));
            mx = fmaxf(mx, __shfl_xor(mx, 2));
            float e0 = __expf(s0 - mx), e1 = __expf(s1 - mx);
            float sm = e0 + e1;
            sm += __shfl_xor(sm, 1);
            sm += __shfl_xor(sm, 2);
            float inv = 1.f / sm;
            probs[prow * 8 + kj]     = e0 * inv;
            probs[prow * 8 + kj + 1] = e1 * inv;
        }
        __syncthreads();

        // PV: thread -> (row, 4 head-dims)
        {
            int row = tid >> 2;
            int p8 = row & ~7;
            int dbase = dgrp * 4;
            float o0 = 0, o1 = 0, o2 = 0, o3 = 0;
            #pragma unroll
            for (int kj = 0; kj < 8; ++kj) {
                float pk = probs[row * 8 + kj];
                const float* vr = vb + (p8 + kj) * 17 + dbase;
                o0 += pk * vr[0]; o1 += pk * vr[1];
                o2 += pk * vr[2]; o3 += pk * vr[3];
            }
            unsigned int w0 = (unsigned int)f2bf(o0) | ((unsigned int)f2bf(o1) << 16);
            unsigned int w1 = (unsigned int)f2bf(o2) | ((unsigned int)f2bf(o3) << 16);
            uint2 pw; pw.x = w0; pw.y = w1;
            *(uint2*)&attn[row][hd * HD + dbase] = pw;
        }
        // no barrier needed here: next staging touches only Bt; the post-staging
        // barrier orders PV completion before q/k/v overwrite.
    }

    // ---------------- proj GEMM: attn(64x128) @ wproj(128x128), K split in halves ----------------
    f32x4 pacc[8];
    #pragma unroll
    for (int nt = 0; nt < 8; ++nt) { pacc[nt].x = 0.f; pacc[nt].y = 0.f; pacc[nt].z = 0.f; pacc[nt].w = 0.f; }

    for (int kh = 0; kh < 2; ++kh) {
        // stage Btp[n][kk] = bf16(wproj[kh*64+kk][n])  (Btp aliases head-phase bufs; those reads are done)
        for (int it = 0; it < 4; ++it) {
            int u = it * 256 + tid;              // 0..1023: k = u>>4 (0..63), ng = u&15
            int k = u >> 4, ng = u & 15;
            const float* wsrc = wproj + (kh * 64 + k) * CDIM + ng * 8;
            float4 wa = *(const float4*)wsrc;
            float4 wb = *(const float4*)(wsrc + 4);
            Btp[(ng * 8 + 0) * 68 + k] = f2bf(wa.x);
            Btp[(ng * 8 + 1) * 68 + k] = f2bf(wa.y);
            Btp[(ng * 8 + 2) * 68 + k] = f2bf(wa.z);
            Btp[(ng * 8 + 3) * 68 + k] = f2bf(wa.w);
            Btp[(ng * 8 + 4) * 68 + k] = f2bf(wb.x);
            Btp[(ng * 8 + 5) * 68 + k] = f2bf(wb.y);
            Btp[(ng * 8 + 6) * 68 + k] = f2bf(wb.z);
            Btp[(ng * 8 + 7) * 68 + k] = f2bf(wb.w);
        }
        __syncthreads();   // staging visible; also orders attn writes (PV) before GEMM reads
        #pragma unroll
        for (int nt = 0; nt < 8; ++nt) {
            #pragma unroll
            for (int ks = 0; ks < 2; ++ks) {
                FragU a, bf;
                const unsigned short* pa = &attn[wv * 16 + lr][kh * 64 + ks * 32 + lg * 4];
                uint2 alo = *(const uint2*)pa;
                uint2 ahi = *(const uint2*)(pa + 16);
                a.u.x = alo.x; a.u.y = alo.y; a.u.z = ahi.x; a.u.w = ahi.y;
                const unsigned short* pb = Btp + (nt * 16 + lr) * 68 + ks * 32 + lg * 4;
                uint2 blo = *(const uint2*)pb;
                uint2 bhi = *(const uint2*)(pb + 16);
                bf.u.x = blo.x; bf.u.y = blo.y; bf.u.z = bhi.x; bf.u.w = bhi.y;
                pacc[nt] = __builtin_amdgcn_mfma_f32_16x16x32_bf16(a.v, bf.v, pacc[nt], 0, 0, 0);
            }
        }
        __syncthreads();   // before restage (kh=0) / before epilogue transpose buffer reuse (kh=1)
    }

    // ---------------- epilogue: bias, transpose via LDS, residual, store (f32) ----------------
    unsigned short* out_t = &xln[0][0];          // [8 n][128 c][8 pix] = 8192 ushorts (fits xln)
    #pragma unroll
    for (int nt = 0; nt < 8; ++nt) {
        int col = nt * 16 + lr;
        float bias = bproj[col];
        #pragma unroll
        for (int j = 0; j < 4; ++j) {
            int row = wv * 16 + lg * 4 + j;      // row = pix*8 + n
            out_t[((row & 7) * CDIM + col) * 8 + (row >> 3)] = f2bf(pacc[nt][j] + bias);
        }
    }
    __syncthreads();
    for (int it = 0; it < 4; ++it) {
        int u = it * 256 + tid;                  // u = n*128 + c
        int gaddr = base + u * HWSZ;
        float4 r0 = *(const float4*)(feat + gaddr);
        float4 r1 = *(const float4*)(feat + gaddr + 4);
        float4 o0, o1;
        o0.x = r0.x + bf2f(out_t[u * 8 + 0]);
        o0.y = r0.y + bf2f(out_t[u * 8 + 1]);
        o0.z = r0.z + bf2f(out_t[u * 8 + 2]);
        o0.w = r0.w + bf2f(out_t[u * 8 + 3]);
        o1.x = r1.x + bf2f(out_t[u * 8 + 4]);
        o1.y = r1.y + bf2f(out_t[u * 8 + 5]);
        o1.z = r1.z + bf2f(out_t[u * 8 + 6]);
        o1.w = r1.w + bf2f(out_t[u * 8 + 7]);
        *(float4*)(outp + gaddr) = o0;
        *(float4*)(outp + gaddr + 4) = o1;
    }
}

extern "C" void kernel_launch(void* const* d_in, const int* in_sizes, int n_in,
                              void* d_out, int out_size, void* d_ws, size_t ws_size,
                              hipStream_t stream) {
    const float* feat  = (const float*)d_in[0];
    const float* wqkv  = (const float*)d_in[1];
    const float* wproj = (const float*)d_in[2];
    const float* bproj = (const float*)d_in[3];
    const float* gamma = (const float*)d_in[4];
    const float* beta  = (const float*)d_in[5];
    float* outp = (float*)d_out;

    dim3 grid(NB * HH * (WWIDTH / PIX));  // 4*96*12 = 4608
    dim3 blockDim(256);
    hipLaunchKernelGGL(cfa_fused, grid, blockDim, 0, stream,
                       feat, wqkv, wproj, bproj, gamma, beta, outp);
}

// Round 3
// 338.765 us; speedup vs baseline: 1.2469x; 1.2469x over previous
//
#include <hip/hip_runtime.h>

#define NFR 8
#define CDIM 128
#define HH 96
#define WW 96
#define NB 4
#define PIX 8
#define HWSZ 9216        // HH*WW

typedef __attribute__((ext_vector_type(8))) short bf16x8;
typedef __attribute__((ext_vector_type(4))) float f32x4;

union FragU { uint4 u; bf16x8 v; };

__device__ inline float bf2f(unsigned short h) {
    unsigned int x = ((unsigned int)h) << 16;
    float f; __builtin_memcpy(&f, &x, 4); return f;
}
__device__ inline unsigned short f2bf(float f) {
    unsigned int x; __builtin_memcpy(&x, &f, 4);
    return (unsigned short)((x + 0x7FFFu + ((x >> 16) & 1u)) >> 16);
}
__device__ inline unsigned int packbf(float a, float b) {
    return (unsigned int)f2bf(a) | ((unsigned int)f2bf(b) << 16);
}

// ---------------------------------------------------------------------------
// ws layout (uint4 units of 16B):
//   [0,    4096) : qk A-frags   ((hd*2+three)*4+ks)*64 + lane   (three: 0=q,1=k)
//   [4096, 6144) : v  B-frags   (hd*4+ks)*64 + lane
//   [6144, 8192) : proj B-frags (nt*4+ks)*64 + lane
// bytes 131072: gammaP f32[128]; 131584: betaP f32[128]   (total 132096 B)
// Fragment element e (0..7) of (ks): channel c = ks*32 + lg*4 + (e&3) + ((e>>2)<<4)
// ---------------------------------------------------------------------------
__global__ __launch_bounds__(256)
void repack_k(const float* __restrict__ wqkv, const float* __restrict__ wproj,
              const float* __restrict__ gamma, const float* __restrict__ beta,
              unsigned short* __restrict__ ws)
{
    int gid = blockIdx.x * 256 + threadIdx.x;
    uint4* wsq = (uint4*)ws;
    int l = gid & 63, lr = l & 15, lg = (l >> 4) & 3;
    if (gid < 8192) {
        int unit = gid >> 6;
        int col, ks, stride;
        const float* src;
        if (unit < 64) {              // qk A-frags: A[m=col][k=c] = wqkv[c][col]
            int t = unit >> 2; ks = unit & 3;
            int hd = t >> 1, three = t & 1;
            col = three * 128 + hd * 16 + lr;
            src = wqkv; stride = 384;
        } else if (unit < 96) {       // v B-frags: B[k=c][n] = wqkv[c][256+hd*16+n]
            int u2 = unit - 64; int hd = u2 >> 2; ks = u2 & 3;
            col = 256 + hd * 16 + lr;
            src = wqkv; stride = 384;
        } else {                      // proj B-frags: B[k=c][n] = wproj[c][n]
            int u3 = unit - 96; int nt = u3 >> 2; ks = u3 & 3;
            col = nt * 16 + lr;
            src = wproj; stride = 128;
        }
        unsigned int dw[4];
        #pragma unroll
        for (int i = 0; i < 4; ++i) {
            int e0 = 2 * i, e1 = 2 * i + 1;
            int c0 = ks * 32 + lg * 4 + (e0 & 3) + ((e0 >> 2) << 4);
            int c1 = ks * 32 + lg * 4 + (e1 & 3) + ((e1 >> 2) << 4);
            dw[i] = packbf(src[c0 * stride + col], src[c1 * stride + col]);
        }
        uint4 o; o.x = dw[0]; o.y = dw[1]; o.z = dw[2]; o.w = dw[3];
        wsq[gid] = o;
    } else if (gid < 8192 + 256) {
        int p = gid - 8192;           // 0..127 gamma, 128..255 beta (permuted)
        int pp = p & 127;
        int ks = pp >> 5, pos = pp & 31;
        int c = ks * 32 + ((pos >> 3) << 2) + (pos & 3) + (((pos >> 2) & 1) << 4);
        ((float*)ws)[32768 + p] = (p < 128) ? gamma[c] : beta[c];
    }
}

// ---------------------------------------------------------------------------
// xln LDS layout: u16 index = ks*2048 + row*32 + pos, pos = f(c&31):
//   c5<16: pos = (c5>>2)*8 + (c5&3);  c5>=16: pos = ((c5&15)>>2)*8 + 4 + (c5&3)
// => lane (lr,lg) fragment for (row,ks) = one aligned 16B chunk (ds_read_b128),
//    and each wave's 64 chunks tile a 1024B-aligned region (conflict-free).
// ---------------------------------------------------------------------------
__global__ __launch_bounds__(256)
void cfa_main(const float* __restrict__ feat, const float* __restrict__ bproj,
              const unsigned short* __restrict__ ws, float* __restrict__ outp)
{
    __shared__ uint4 xlnU4[1024];                    // 16 KB
    unsigned short* xln16 = (unsigned short*)xlnU4;

    const int tid = threadIdx.x;
    const int blk = blockIdx.x;
    const int wt = blk % 12, h = (blk / 12) % 96, b = blk / (12 * 96);
    const int base = ((b * NFR) * CDIM) * HWSZ + h * WW + wt * PIX;

    // ---- phase 1: stage features (f32 -> bf16, permuted layout) ----
    for (int it = 0; it < 4; ++it) {
        int u = it * 256 + tid;                      // u = n*128 + c
        int n = u >> 7, c = u & 127;
        const float* src = feat + base + u * HWSZ;   // 8 consecutive pixels
        float4 ra = *(const float4*)src;
        float4 rb = *(const float4*)(src + 4);
        int ks = c >> 5, c5 = c & 31;
        int pos = (c5 < 16) ? (((c5 >> 2) << 3) + (c5 & 3))
                            : ((((c5 & 15) >> 2) << 3) + 4 + (c5 & 3));
        int bi = ks * 2048 + n * 32 + pos;           // + p*256 for pixel p
        xln16[bi + 0 * 256] = f2bf(ra.x);
        xln16[bi + 1 * 256] = f2bf(ra.y);
        xln16[bi + 2 * 256] = f2bf(ra.z);
        xln16[bi + 3 * 256] = f2bf(ra.w);
        xln16[bi + 4 * 256] = f2bf(rb.x);
        xln16[bi + 5 * 256] = f2bf(rb.y);
        xln16[bi + 6 * 256] = f2bf(rb.z);
        xln16[bi + 7 * 256] = f2bf(rb.w);
    }
    __syncthreads();

    // ---- phase 2: LayerNorm in-place (permuted gamma/beta from ws) ----
    {
        int row = tid >> 2, ks = tid & 3;
        int baseq = ks * 256 + row * 4;              // uint4 index
        uint4 ch[4];
        #pragma unroll
        for (int j = 0; j < 4; ++j) ch[j] = xlnU4[baseq + ((j + row + ks) & 3)];
        float s = 0.f, ss = 0.f;
        #pragma unroll
        for (int j = 0; j < 4; ++j) {
            const unsigned short* e = (const unsigned short*)&ch[j];
            #pragma unroll
            for (int b8 = 0; b8 < 8; ++b8) { float x = bf2f(e[b8]); s += x; ss += x * x; }
        }
        s += __shfl_xor(s, 1); ss += __shfl_xor(ss, 1);
        s += __shfl_xor(s, 2); ss += __shfl_xor(ss, 2);
        float mu = s * (1.f / 128.f);
        float var = ss * (1.f / 128.f) - mu * mu;
        float rstd = rsqrtf(var + 1e-5f);
        const float* gP = (const float*)ws + 32768;
        const float* bP = gP + 128;
        #pragma unroll
        for (int j = 0; j < 4; ++j) {
            int cj = (j + row + ks) & 3;
            const unsigned short* e = (const unsigned short*)&ch[j];
            unsigned int dw[4];
            #pragma unroll
            for (int i = 0; i < 4; ++i) {
                int p0 = cj * 8 + 2 * i, p1 = p0 + 1;
                float x0 = (bf2f(e[2 * i])     - mu) * rstd * gP[ks * 32 + p0] + bP[ks * 32 + p0];
                float x1 = (bf2f(e[2 * i + 1]) - mu) * rstd * gP[ks * 32 + p1] + bP[ks * 32 + p1];
                dw[i] = packbf(x0, x1);
            }
            uint4 o; o.x = dw[0]; o.y = dw[1]; o.z = dw[2]; o.w = dw[3];
            xlnU4[baseq + cj] = o;
        }
    }
    // no barrier: wave w LN'd rows 16w..16w+15 and reads only those below.

    const int wv = tid >> 6, l = tid & 63, lr = l & 15, lg = l >> 4;
    const uint4* wsq = (const uint4*)ws;

    // ---- x fragments (shared by QK^T-GEMM as B and V-GEMM as A) ----
    FragU xf[4];
    #pragma unroll
    for (int ks = 0; ks < 4; ++ks)
        xf[ks].u = xlnU4[ks * 256 + (wv * 16 + lr) * 4 + lg];

    const bool valid = ((lg >> 1) == (lr >> 3));     // same-pixel (q,k) pairs
    FragU pa[4];                                     // proj A-frags (built per 2 heads)
    #pragma unroll
    for (int ks = 0; ks < 4; ++ks) { pa[ks].u.x = 0; pa[ks].u.y = 0; pa[ks].u.z = 0; pa[ks].u.w = 0; }

    // ---- per-head: all-register qkv + attention ----
    #pragma unroll
    for (int hd = 0; hd < 8; ++hd) {
        uint4 qa[4], ka[4], va[4];
        #pragma unroll
        for (int ks = 0; ks < 4; ++ks) {
            qa[ks] = wsq[((hd * 2 + 0) * 4 + ks) * 64 + l];
            ka[ks] = wsq[((hd * 2 + 1) * 4 + ks) * 64 + l];
            va[ks] = wsq[4096 + (hd * 4 + ks) * 64 + l];
        }
        f32x4 q = {0,0,0,0}, k = {0,0,0,0}, v = {0,0,0,0};
        #pragma unroll
        for (int ks = 0; ks < 4; ++ks) {
            FragU A, B, V2; A.u = qa[ks]; B.u = ka[ks]; V2.u = va[ks];
            q = __builtin_amdgcn_mfma_f32_16x16x32_bf16(A.v,  xf[ks].v, q, 0, 0, 0);   // Q^T
            k = __builtin_amdgcn_mfma_f32_16x16x32_bf16(B.v,  xf[ks].v, k, 0, 0, 0);   // K^T
            v = __builtin_amdgcn_mfma_f32_16x16x32_bf16(xf[ks].v, V2.v, v, 0, 0, 0);   // V
        }
        // lane now: Q/K[token=lr][d=lg*4+j], V[token=lg*4+j][d=lr]
        FragU qb, kb, vb;
        qb.u.x = packbf(q.x, q.y); qb.u.y = packbf(q.z, q.w); qb.u.z = 0; qb.u.w = 0;
        kb.u.x = packbf(k.x, k.y); kb.u.y = packbf(k.z, k.w); kb.u.z = 0; kb.u.w = 0;
        vb.u.x = packbf(v.x, v.y); vb.u.y = packbf(v.z, v.w); vb.u.z = 0; vb.u.w = 0;
        f32x4 zz = {0,0,0,0};
        // S^T = K·Q^T (K=16, upper half zero): lane holds S[q=lr][k=lg*4+j]
        f32x4 st = __builtin_amdgcn_mfma_f32_16x16x32_bf16(kb.v, qb.v, zz, 0, 0, 0);
        float sc0 = st.x * 0.25f, sc1 = st.y * 0.25f, sc2 = st.z * 0.25f, sc3 = st.w * 0.25f;
        float m = valid ? fmaxf(fmaxf(sc0, sc1), fmaxf(sc2, sc3)) : -3.0e38f;
        m = fmaxf(m, __shfl_xor(m, 16));
        float e0 = valid ? __expf(sc0 - m) : 0.f, e1 = valid ? __expf(sc1 - m) : 0.f;
        float e2 = valid ? __expf(sc2 - m) : 0.f, e3 = valid ? __expf(sc3 - m) : 0.f;
        float sm = e0 + e1 + e2 + e3; sm += __shfl_xor(sm, 16);
        float inv = 1.f / sm;
        float p0 = valid ? e0 * inv : 0.f, p1 = valid ? e1 * inv : 0.f;
        float p2 = valid ? e2 * inv : 0.f, p3 = valid ? e3 * inv : 0.f;
        FragU pb; pb.u.x = packbf(p0, p1); pb.u.y = packbf(p2, p3); pb.u.z = 0; pb.u.w = 0;
        // O^T = V^T·P^T: lane holds O[q=lr][d=lg*4+j]
        f32x4 o = __builtin_amdgcn_mfma_f32_16x16x32_bf16(vb.v, pb.v, zz, 0, 0, 0);
        if ((hd & 1) == 0) { pa[hd >> 1].u.x = packbf(o.x, o.y); pa[hd >> 1].u.y = packbf(o.z, o.w); }
        else               { pa[hd >> 1].u.z = packbf(o.x, o.y); pa[hd >> 1].u.w = packbf(o.z, o.w); }
    }

    // ---- proj GEMM: O(64x128) @ wproj(128x128), A-frags already in regs ----
    f32x4 pacc[8];
    #pragma unroll
    for (int nt = 0; nt < 8; ++nt) pacc[nt] = (f32x4){0,0,0,0};
    #pragma unroll
    for (int nt = 0; nt < 8; ++nt) {
        #pragma unroll
        for (int ks = 0; ks < 4; ++ks) {
            FragU B; B.u = wsq[6144 + (nt * 4 + ks) * 64 + l];
            pacc[nt] = __builtin_amdgcn_mfma_f32_16x16x32_bf16(pa[ks].v, B.v, pacc[nt], 0, 0, 0);
        }
    }

    __syncthreads();                                 // xln dead -> reuse as out_t
    // ---- epilogue: bias, XOR-swizzled transpose, residual, store ----
    unsigned short* out_t = xln16;                   // [n][col^n][pix], 8192 u16
    #pragma unroll
    for (int nt = 0; nt < 8; ++nt) {
        int col = nt * 16 + lr;
        float bias = bproj[col];
        #pragma unroll
        for (int j = 0; j < 4; ++j) {
            int row = wv * 16 + lg * 4 + j;          // row = pix*8 + n
            int n = row & 7, p = row >> 3;
            out_t[n * 1024 + (col ^ n) * 8 + p] = f2bf(pacc[nt][j] + bias);
        }
    }
    __syncthreads();
    for (int it = 0; it < 4; ++it) {
        int u = it * 256 + tid;                      // u = n*128 + c
        int n = u >> 7, c = u & 127;
        int gaddr = base + u * HWSZ;
        float4 r0 = *(const float4*)(feat + gaddr);
        float4 r1 = *(const float4*)(feat + gaddr + 4);
        uint4 tv = *(const uint4*)(out_t + n * 1024 + (c ^ n) * 8);
        const unsigned short* tp = (const unsigned short*)&tv;
        float4 o0, o1;
        o0.x = r0.x + bf2f(tp[0]); o0.y = r0.y + bf2f(tp[1]);
        o0.z = r0.z + bf2f(tp[2]); o0.w = r0.w + bf2f(tp[3]);
        o1.x = r1.x + bf2f(tp[4]); o1.y = r1.y + bf2f(tp[5]);
        o1.z = r1.z + bf2f(tp[6]); o1.w = r1.w + bf2f(tp[7]);
        *(float4*)(outp + gaddr) = o0;
        *(float4*)(outp + gaddr + 4) = o1;
    }
}

extern "C" void kernel_launch(void* const* d_in, const int* in_sizes, int n_in,
                              void* d_out, int out_size, void* d_ws, size_t ws_size,
                              hipStream_t stream) {
    const float* feat  = (const float*)d_in[0];
    const float* wqkv  = (const float*)d_in[1];
    const float* wproj = (const float*)d_in[2];
    const float* bproj = (const float*)d_in[3];
    const float* gamma = (const float*)d_in[4];
    const float* beta  = (const float*)d_in[5];
    unsigned short* ws = (unsigned short*)d_ws;      // needs 132096 B
    float* outp = (float*)d_out;

    hipLaunchKernelGGL(repack_k, dim3(33), dim3(256), 0, stream,
                       wqkv, wproj, gamma, beta, ws);
    hipLaunchKernelGGL(cfa_main, dim3(NB * HH * (WW / PIX)), dim3(256), 0, stream,
                       feat, bproj, ws, outp);
}

// Round 4
// 198.453 us; speedup vs baseline: 2.1285x; 1.7070x over previous
//
#include <hip/hip_runtime.h>

#define NFR 8
#define CDIM 128
#define HH 96
#define WW 96
#define NB 4
#define PIX 8
#define HWSZ 9216        // HH*WW
#define NBLK 4608        // NB*HH*(WW/PIX)
#define NXCD 8
#define CPX (NBLK / NXCD)  // 576

typedef __attribute__((ext_vector_type(8))) short bf16x8;
typedef __attribute__((ext_vector_type(4))) float f32x4;

union FragU { uint4 u; bf16x8 v; };

__device__ inline float bf2f(unsigned short h) {
    unsigned int x = ((unsigned int)h) << 16;
    float f; __builtin_memcpy(&f, &x, 4); return f;
}
__device__ inline unsigned short f2bf(float f) {
    unsigned int x; __builtin_memcpy(&x, &f, 4);
    return (unsigned short)((x + 0x7FFFu + ((x >> 16) & 1u)) >> 16);
}
__device__ inline unsigned int packbf(float a, float b) {
    return (unsigned int)f2bf(a) | ((unsigned int)f2bf(b) << 16);
}

// ---------------------------------------------------------------------------
// ws layout (uint4 units of 16B):
//   [0,    4096) : qk A-frags   ((hd*2+three)*4+ks)*64 + lane   (three: 0=q,1=k)
//   [4096, 6144) : v  B-frags   (hd*4+ks)*64 + lane
//   [6144, 8192) : proj B-frags (nt*4+ks)*64 + lane
// bytes 131072: gammaP f32[128]; 131584: betaP f32[128]   (total 132096 B)
// Fragment element e (0..7) of (ks): channel c = ks*32 + lg*4 + (e&3) + ((e>>2)<<4)
// ---------------------------------------------------------------------------
__global__ __launch_bounds__(256)
void repack_k(const float* __restrict__ wqkv, const float* __restrict__ wproj,
              const float* __restrict__ gamma, const float* __restrict__ beta,
              unsigned short* __restrict__ ws)
{
    int gid = blockIdx.x * 256 + threadIdx.x;
    uint4* wsq = (uint4*)ws;
    int l = gid & 63, lr = l & 15, lg = (l >> 4) & 3;
    if (gid < 8192) {
        int unit = gid >> 6;
        int col, ks, stride;
        const float* src;
        if (unit < 64) {              // qk A-frags: A[m=col][k=c] = wqkv[c][col]
            int t = unit >> 2; ks = unit & 3;
            int hd = t >> 1, three = t & 1;
            col = three * 128 + hd * 16 + lr;
            src = wqkv; stride = 384;
        } else if (unit < 96) {       // v B-frags: B[k=c][n] = wqkv[c][256+hd*16+n]
            int u2 = unit - 64; int hd = u2 >> 2; ks = u2 & 3;
            col = 256 + hd * 16 + lr;
            src = wqkv; stride = 384;
        } else {                      // proj B-frags: B[k=c][n] = wproj[c][n]
            int u3 = unit - 96; int nt = u3 >> 2; ks = u3 & 3;
            col = nt * 16 + lr;
            src = wproj; stride = 128;
        }
        unsigned int dw[4];
        #pragma unroll
        for (int i = 0; i < 4; ++i) {
            int e0 = 2 * i, e1 = 2 * i + 1;
            int c0 = ks * 32 + lg * 4 + (e0 & 3) + ((e0 >> 2) << 4);
            int c1 = ks * 32 + lg * 4 + (e1 & 3) + ((e1 >> 2) << 4);
            dw[i] = packbf(src[c0 * stride + col], src[c1 * stride + col]);
        }
        uint4 o; o.x = dw[0]; o.y = dw[1]; o.z = dw[2]; o.w = dw[3];
        wsq[gid] = o;
    } else if (gid < 8192 + 256) {
        int p = gid - 8192;           // 0..127 gamma, 128..255 beta (permuted)
        int pp = p & 127;
        int ks = pp >> 5, pos = pp & 31;
        int c = ks * 32 + ((pos >> 3) << 2) + (pos & 3) + (((pos >> 2) & 1) << 4);
        ((float*)ws)[32768 + p] = (p < 128) ? gamma[c] : beta[c];
    }
}

// ---------------------------------------------------------------------------
// xln LDS layout: u16 index = ks*2048 + row*32 + pos, pos = f(c&31):
//   c5<16: pos = (c5>>2)*8 + (c5&3);  c5>=16: pos = ((c5&15)>>2)*8 + 4 + (c5&3)
// => lane (lr,lg) fragment for (row,ks) = one aligned 16B chunk (ds_read_b128),
//    and each wave's 64 chunks tile a 1024B-aligned region (conflict-free).
// ---------------------------------------------------------------------------
__global__ __launch_bounds__(256)
void cfa_main(const float* __restrict__ feat, const float* __restrict__ bproj,
              const unsigned short* __restrict__ ws, float* __restrict__ outp)
{
    __shared__ uint4 xlnU4[1024];                    // 16 KB
    unsigned short* xln16 = (unsigned short*)xlnU4;

    const int tid = threadIdx.x;
    // XCD-chunked swizzle: dispatcher round-robins blockIdx.x across the 8
    // XCDs; remap so each XCD owns a CONTIGUOUS range of logical tiles. The 4
    // adjacent wt-tiles sharing each 128-B feature line then run on the same
    // XCD concurrently -> line fetched from HBM once, residual re-read L2-hot.
    const int blk = (blockIdx.x % NXCD) * CPX + blockIdx.x / NXCD;
    const int wt = blk % 12, h = (blk / 12) % 96, b = blk / (12 * 96);
    const int base = ((b * NFR) * CDIM) * HWSZ + h * WW + wt * PIX;

    // ---- phase 1: stage features (f32 -> bf16, permuted layout) ----
    for (int it = 0; it < 4; ++it) {
        int u = it * 256 + tid;                      // u = n*128 + c
        int n = u >> 7, c = u & 127;
        const float* src = feat + base + u * HWSZ;   // 8 consecutive pixels
        float4 ra = *(const float4*)src;
        float4 rb = *(const float4*)(src + 4);
        int ks = c >> 5, c5 = c & 31;
        int pos = (c5 < 16) ? (((c5 >> 2) << 3) + (c5 & 3))
                            : ((((c5 & 15) >> 2) << 3) + 4 + (c5 & 3));
        int bi = ks * 2048 + n * 32 + pos;           // + p*256 for pixel p
        xln16[bi + 0 * 256] = f2bf(ra.x);
        xln16[bi + 1 * 256] = f2bf(ra.y);
        xln16[bi + 2 * 256] = f2bf(ra.z);
        xln16[bi + 3 * 256] = f2bf(ra.w);
        xln16[bi + 4 * 256] = f2bf(rb.x);
        xln16[bi + 5 * 256] = f2bf(rb.y);
        xln16[bi + 6 * 256] = f2bf(rb.z);
        xln16[bi + 7 * 256] = f2bf(rb.w);
    }
    __syncthreads();

    // ---- phase 2: LayerNorm in-place (permuted gamma/beta from ws) ----
    {
        int row = tid >> 2, ks = tid & 3;
        int baseq = ks * 256 + row * 4;              // uint4 index
        uint4 ch[4];
        #pragma unroll
        for (int j = 0; j < 4; ++j) ch[j] = xlnU4[baseq + ((j + row + ks) & 3)];
        float s = 0.f, ss = 0.f;
        #pragma unroll
        for (int j = 0; j < 4; ++j) {
            const unsigned short* e = (const unsigned short*)&ch[j];
            #pragma unroll
            for (int b8 = 0; b8 < 8; ++b8) { float x = bf2f(e[b8]); s += x; ss += x * x; }
        }
        s += __shfl_xor(s, 1); ss += __shfl_xor(ss, 1);
        s += __shfl_xor(s, 2); ss += __shfl_xor(ss, 2);
        float mu = s * (1.f / 128.f);
        float var = ss * (1.f / 128.f) - mu * mu;
        float rstd = rsqrtf(var + 1e-5f);
        const float* gP = (const float*)ws + 32768;
        const float* bP = gP + 128;
        #pragma unroll
        for (int j = 0; j < 4; ++j) {
            int cj = (j + row + ks) & 3;
            const unsigned short* e = (const unsigned short*)&ch[j];
            unsigned int dw[4];
            #pragma unroll
            for (int i = 0; i < 4; ++i) {
                int p0 = cj * 8 + 2 * i, p1 = p0 + 1;
                float x0 = (bf2f(e[2 * i])     - mu) * rstd * gP[ks * 32 + p0] + bP[ks * 32 + p0];
                float x1 = (bf2f(e[2 * i + 1]) - mu) * rstd * gP[ks * 32 + p1] + bP[ks * 32 + p1];
                dw[i] = packbf(x0, x1);
            }
            uint4 o; o.x = dw[0]; o.y = dw[1]; o.z = dw[2]; o.w = dw[3];
            xlnU4[baseq + cj] = o;
        }
    }
    // no barrier: wave w LN'd rows 16w..16w+15 and reads only those below.

    const int wv = tid >> 6, l = tid & 63, lr = l & 15, lg = l >> 4;
    const uint4* wsq = (const uint4*)ws;

    // ---- x fragments (shared by QK^T-GEMM as B and V-GEMM as A) ----
    FragU xf[4];
    #pragma unroll
    for (int ks = 0; ks < 4; ++ks)
        xf[ks].u = xlnU4[ks * 256 + (wv * 16 + lr) * 4 + lg];

    const bool valid = ((lg >> 1) == (lr >> 3));     // same-pixel (q,k) pairs
    FragU pa[4];                                     // proj A-frags (built per 2 heads)
    #pragma unroll
    for (int ks = 0; ks < 4; ++ks) { pa[ks].u.x = 0; pa[ks].u.y = 0; pa[ks].u.z = 0; pa[ks].u.w = 0; }

    // ---- per-head: all-register qkv + attention ----
    #pragma unroll
    for (int hd = 0; hd < 8; ++hd) {
        uint4 qa[4], ka[4], va[4];
        #pragma unroll
        for (int ks = 0; ks < 4; ++ks) {
            qa[ks] = wsq[((hd * 2 + 0) * 4 + ks) * 64 + l];
            ka[ks] = wsq[((hd * 2 + 1) * 4 + ks) * 64 + l];
            va[ks] = wsq[4096 + (hd * 4 + ks) * 64 + l];
        }
        f32x4 q = {0,0,0,0}, k = {0,0,0,0}, v = {0,0,0,0};
        #pragma unroll
        for (int ks = 0; ks < 4; ++ks) {
            FragU A, B, V2; A.u = qa[ks]; B.u = ka[ks]; V2.u = va[ks];
            q = __builtin_amdgcn_mfma_f32_16x16x32_bf16(A.v,  xf[ks].v, q, 0, 0, 0);   // Q^T
            k = __builtin_amdgcn_mfma_f32_16x16x32_bf16(B.v,  xf[ks].v, k, 0, 0, 0);   // K^T
            v = __builtin_amdgcn_mfma_f32_16x16x32_bf16(xf[ks].v, V2.v, v, 0, 0, 0);   // V
        }
        // lane now: Q/K[token=lr][d=lg*4+j], V[token=lg*4+j][d=lr]
        FragU qb, kb, vb;
        qb.u.x = packbf(q.x, q.y); qb.u.y = packbf(q.z, q.w); qb.u.z = 0; qb.u.w = 0;
        kb.u.x = packbf(k.x, k.y); kb.u.y = packbf(k.z, k.w); kb.u.z = 0; kb.u.w = 0;
        vb.u.x = packbf(v.x, v.y); vb.u.y = packbf(v.z, v.w); vb.u.z = 0; vb.u.w = 0;
        f32x4 zz = {0,0,0,0};
        // S^T = K·Q^T (K=16, upper half zero): lane holds S[q=lr][k=lg*4+j]
        f32x4 st = __builtin_amdgcn_mfma_f32_16x16x32_bf16(kb.v, qb.v, zz, 0, 0, 0);
        float sc0 = st.x * 0.25f, sc1 = st.y * 0.25f, sc2 = st.z * 0.25f, sc3 = st.w * 0.25f;
        float m = valid ? fmaxf(fmaxf(sc0, sc1), fmaxf(sc2, sc3)) : -3.0e38f;
        m = fmaxf(m, __shfl_xor(m, 16));
        float e0 = valid ? __expf(sc0 - m) : 0.f, e1 = valid ? __expf(sc1 - m) : 0.f;
        float e2 = valid ? __expf(sc2 - m) : 0.f, e3 = valid ? __expf(sc3 - m) : 0.f;
        float sm = e0 + e1 + e2 + e3; sm += __shfl_xor(sm, 16);
        float inv = 1.f / sm;
        float p0 = valid ? e0 * inv : 0.f, p1 = valid ? e1 * inv : 0.f;
        float p2 = valid ? e2 * inv : 0.f, p3 = valid ? e3 * inv : 0.f;
        FragU pb; pb.u.x = packbf(p0, p1); pb.u.y = packbf(p2, p3); pb.u.z = 0; pb.u.w = 0;
        // O^T = V^T·P^T: lane holds O[q=lr][d=lg*4+j]
        f32x4 o = __builtin_amdgcn_mfma_f32_16x16x32_bf16(vb.v, pb.v, zz, 0, 0, 0);
        if ((hd & 1) == 0) { pa[hd >> 1].u.x = packbf(o.x, o.y); pa[hd >> 1].u.y = packbf(o.z, o.w); }
        else               { pa[hd >> 1].u.z = packbf(o.x, o.y); pa[hd >> 1].u.w = packbf(o.z, o.w); }
    }

    // ---- proj GEMM: O(64x128) @ wproj(128x128), A-frags already in regs ----
    f32x4 pacc[8];
    #pragma unroll
    for (int nt = 0; nt < 8; ++nt) pacc[nt] = (f32x4){0,0,0,0};
    #pragma unroll
    for (int nt = 0; nt < 8; ++nt) {
        #pragma unroll
        for (int ks = 0; ks < 4; ++ks) {
            FragU B; B.u = wsq[6144 + (nt * 4 + ks) * 64 + l];
            pacc[nt] = __builtin_amdgcn_mfma_f32_16x16x32_bf16(pa[ks].v, B.v, pacc[nt], 0, 0, 0);
        }
    }

    __syncthreads();                                 // xln dead -> reuse as out_t
    // ---- epilogue: bias, XOR-swizzled transpose, residual, store ----
    unsigned short* out_t = xln16;                   // [n][col^n][pix], 8192 u16
    #pragma unroll
    for (int nt = 0; nt < 8; ++nt) {
        int col = nt * 16 + lr;
        float bias = bproj[col];
        #pragma unroll
        for (int j = 0; j < 4; ++j) {
            int row = wv * 16 + lg * 4 + j;          // row = pix*8 + n
            int n = row & 7, p = row >> 3;
            out_t[n * 1024 + (col ^ n) * 8 + p] = f2bf(pacc[nt][j] + bias);
        }
    }
    __syncthreads();
    for (int it = 0; it < 4; ++it) {
        int u = it * 256 + tid;                      // u = n*128 + c
        int n = u >> 7, c = u & 127;
        int gaddr = base + u * HWSZ;
        float4 r0 = *(const float4*)(feat + gaddr);
        float4 r1 = *(const float4*)(feat + gaddr + 4);
        uint4 tv = *(const uint4*)(out_t + n * 1024 + (c ^ n) * 8);
        const unsigned short* tp = (const unsigned short*)&tv;
        float4 o0, o1;
        o0.x = r0.x + bf2f(tp[0]); o0.y = r0.y + bf2f(tp[1]);
        o0.z = r0.z + bf2f(tp[2]); o0.w = r0.w + bf2f(tp[3]);
        o1.x = r1.x + bf2f(tp[4]); o1.y = r1.y + bf2f(tp[5]);
        o1.z = r1.z + bf2f(tp[6]); o1.w = r1.w + bf2f(tp[7]);
        *(float4*)(outp + gaddr) = o0;
        *(float4*)(outp + gaddr + 4) = o1;
    }
}

extern "C" void kernel_launch(void* const* d_in, const int* in_sizes, int n_in,
                              void* d_out, int out_size, void* d_ws, size_t ws_size,
                              hipStream_t stream) {
    const float* feat  = (const float*)d_in[0];
    const float* wqkv  = (const float*)d_in[1];
    const float* wproj = (const float*)d_in[2];
    const float* bproj = (const float*)d_in[3];
    const float* gamma = (const float*)d_in[4];
    const float* beta  = (const float*)d_in[5];
    unsigned short* ws = (unsigned short*)d_ws;      // needs 132096 B
    float* outp = (float*)d_out;

    hipLaunchKernelGGL(repack_k, dim3(33), dim3(256), 0, stream,
                       wqkv, wproj, gamma, beta, ws);
    hipLaunchKernelGGL(cfa_main, dim3(NBLK), dim3(256), 0, stream,
                       feat, bproj, ws, outp);
}

// Round 7
// 168.688 us; speedup vs baseline: 2.5041x; 1.1765x over previous
//
#include <hip/hip_runtime.h>

#define NFR 8
#define CDIM 128
#define HH 96
#define WW 96
#define NB 4
#define HWSZ 9216        // HH*WW
#define NBLK 2304        // NB*HH*(WW/16)
#define NXCD 8
#define CPX (NBLK / NXCD)  // 288

typedef __attribute__((ext_vector_type(8))) short bf16x8;
typedef __attribute__((ext_vector_type(4))) float f32x4;

union FragU { uint4 u; bf16x8 v; };

__device__ inline float bf2f(unsigned short h) {
    unsigned int x = ((unsigned int)h) << 16;
    float f; __builtin_memcpy(&f, &x, 4); return f;
}
__device__ inline unsigned short f2bf(float f) {
    unsigned int x; __builtin_memcpy(&x, &f, 4);
    return (unsigned short)((x + 0x7FFFu + ((x >> 16) & 1u)) >> 16);
}
__device__ inline unsigned int packbf(float a, float b) {
    return (unsigned int)f2bf(a) | ((unsigned int)f2bf(b) << 16);
}

// ---------------------------------------------------------------------------
// ws layout (uint4 units of 16B):
//   [0,    4096) : qk A-frags   ((hd*2+three)*4+ks)*64 + lane   (three: 0=q,1=k)
//   [4096, 6144) : v  B-frags   (hd*4+ks)*64 + lane
//   [6144, 8192) : proj B-frags (nt*4+ks)*64 + lane
// bytes 131072: gammaP f32[128]; 131584: betaP f32[128]   (total 132096 B)
// Fragment element e (0..7) of (ks): channel c = ks*32 + lg*4 + (e&3) + ((e>>2)<<4)
// ---------------------------------------------------------------------------
__global__ __launch_bounds__(256)
void repack_k(const float* __restrict__ wqkv, const float* __restrict__ wproj,
              const float* __restrict__ gamma, const float* __restrict__ beta,
              unsigned short* __restrict__ ws)
{
    int gid = blockIdx.x * 256 + threadIdx.x;
    uint4* wsq = (uint4*)ws;
    int l = gid & 63, lr = l & 15, lg = (l >> 4) & 3;
    if (gid < 8192) {
        int unit = gid >> 6;
        int col, ks, stride;
        const float* src;
        if (unit < 64) {              // qk A-frags: A[m=col][k=c] = wqkv[c][col]
            int t = unit >> 2; ks = unit & 3;
            int hd = t >> 1, three = t & 1;
            col = three * 128 + hd * 16 + lr;
            src = wqkv; stride = 384;
        } else if (unit < 96) {       // v B-frags: B[k=c][n] = wqkv[c][256+hd*16+n]
            int u2 = unit - 64; int hd = u2 >> 2; ks = u2 & 3;
            col = 256 + hd * 16 + lr;
            src = wqkv; stride = 384;
        } else {                      // proj B-frags: B[k=c][n] = wproj[c][n]
            int u3 = unit - 96; int nt = u3 >> 2; ks = u3 & 3;
            col = nt * 16 + lr;
            src = wproj; stride = 128;
        }
        unsigned int dw[4];
        #pragma unroll
        for (int i = 0; i < 4; ++i) {
            int e0 = 2 * i, e1 = 2 * i + 1;
            int c0 = ks * 32 + lg * 4 + (e0 & 3) + ((e0 >> 2) << 4);
            int c1 = ks * 32 + lg * 4 + (e1 & 3) + ((e1 >> 2) << 4);
            dw[i] = packbf(src[c0 * stride + col], src[c1 * stride + col]);
        }
        uint4 o; o.x = dw[0]; o.y = dw[1]; o.z = dw[2]; o.w = dw[3];
        wsq[gid] = o;
    } else if (gid < 8192 + 256) {
        int p = gid - 8192;           // 0..127 gamma, 128..255 beta (permuted)
        int pp = p & 127;
        int ks = pp >> 5, pos = pp & 31;
        int c = ks * 32 + ((pos >> 3) << 2) + (pos & 3) + (((pos >> 2) & 1) << 4);
        ((float*)ws)[32768 + p] = (p < 128) ? gamma[c] : beta[c];
    }
}

// all-register attention for one head, one 64-row group
__device__ inline f32x4 attn_ov(f32x4 q, f32x4 k, f32x4 v, bool valid) {
    FragU qb, kb, vb;
    qb.u.x = packbf(q.x, q.y); qb.u.y = packbf(q.z, q.w); qb.u.z = 0; qb.u.w = 0;
    kb.u.x = packbf(k.x, k.y); kb.u.y = packbf(k.z, k.w); kb.u.z = 0; kb.u.w = 0;
    vb.u.x = packbf(v.x, v.y); vb.u.y = packbf(v.z, v.w); vb.u.z = 0; vb.u.w = 0;
    f32x4 zz = {0,0,0,0};
    // S^T = K·Q^T (K=16, upper half zero): lane holds S[q=lr][k=lg*4+j]
    f32x4 st = __builtin_amdgcn_mfma_f32_16x16x32_bf16(kb.v, qb.v, zz, 0, 0, 0);
    float sc0 = st.x * 0.25f, sc1 = st.y * 0.25f, sc2 = st.z * 0.25f, sc3 = st.w * 0.25f;
    float m = valid ? fmaxf(fmaxf(sc0, sc1), fmaxf(sc2, sc3)) : -3.0e38f;
    m = fmaxf(m, __shfl_xor(m, 16));
    float e0 = valid ? __expf(sc0 - m) : 0.f, e1 = valid ? __expf(sc1 - m) : 0.f;
    float e2 = valid ? __expf(sc2 - m) : 0.f, e3 = valid ? __expf(sc3 - m) : 0.f;
    float sm = e0 + e1 + e2 + e3; sm += __shfl_xor(sm, 16);
    float inv = 1.f / sm;
    FragU pb;
    pb.u.x = packbf(valid ? e0 * inv : 0.f, valid ? e1 * inv : 0.f);
    pb.u.y = packbf(valid ? e2 * inv : 0.f, valid ? e3 * inv : 0.f);
    pb.u.z = 0; pb.u.w = 0;
    // O^T = V^T·P^T: lane holds O[q=lr][d=lg*4+j]
    return __builtin_amdgcn_mfma_f32_16x16x32_bf16(vb.v, pb.v, zz, 0, 0, 0);
}

// ---------------------------------------------------------------------------
// xln LDS: two 16KB groups (pixels 0-7, 8-15). Within a group, u16 index =
// ks*2048 + row*32 + pos (row = pix_in_group*8 + n; pos = frag permutation of
// c&31) so each lane's MFMA fragment is one aligned ds_read_b128 and a wave
// tiles 1024B regions.
// ---------------------------------------------------------------------------
__global__ __launch_bounds__(256)
void cfa_main(const float* __restrict__ feat, const float* __restrict__ bproj,
              const unsigned short* __restrict__ ws, float* __restrict__ outp)
{
    __shared__ uint4 xlnU4[2048];                    // 32 KB
    unsigned short* xln16 = (unsigned short*)xlnU4;

    const int tid = threadIdx.x;
    const int blk = (int)(blockIdx.x % NXCD) * CPX + (int)blockIdx.x / NXCD;
    const int wt = blk % 6, h = (blk / 6) % 96, b = blk / (6 * 96);
    const int base = ((b * NFR) * CDIM) * HWSZ + h * WW + wt * 16;

    // ---- phase 1: stage 16 pixels (f32 -> bf16, round-4-style u16 writes) ----
    for (int it = 0; it < 8; ++it) {
        int u = it * 256 + tid;                      // 0..2047 = g*1024 + n*128 + c
        int g = u >> 10, r = u & 1023;
        int n = r >> 7, c = r & 127;
        const float* src = feat + base + (n * CDIM + c) * HWSZ + g * 8;
        float4 ra = *(const float4*)src;             // pixels g*8 + 0..3
        float4 rb = *(const float4*)(src + 4);       // pixels g*8 + 4..7
        int ks = c >> 5, c5 = c & 31;
        int pos = (c5 < 16) ? (((c5 >> 2) << 3) + (c5 & 3))
                            : ((((c5 & 15) >> 2) << 3) + 4 + (c5 & 3));
        int bi = g * 8192 + ks * 2048 + n * 32 + pos;  // + p*256 per pixel-in-group
        xln16[bi + 0 * 256] = f2bf(ra.x);
        xln16[bi + 1 * 256] = f2bf(ra.y);
        xln16[bi + 2 * 256] = f2bf(ra.z);
        xln16[bi + 3 * 256] = f2bf(ra.w);
        xln16[bi + 4 * 256] = f2bf(rb.x);
        xln16[bi + 5 * 256] = f2bf(rb.y);
        xln16[bi + 6 * 256] = f2bf(rb.z);
        xln16[bi + 7 * 256] = f2bf(rb.w);
    }
    __syncthreads();

    // ---- phase 2: LayerNorm in-place, both groups ----
    {
        const float* gP = (const float*)ws + 32768;
        const float* bP = gP + 128;
        int rr = tid >> 2, ks = tid & 3;
        #pragma unroll
        for (int g = 0; g < 2; ++g) {
            int baseq = g * 1024 + ks * 256 + rr * 4;
            uint4 ch[4];
            #pragma unroll
            for (int j = 0; j < 4; ++j) ch[j] = xlnU4[baseq + ((j + rr + ks) & 3)];
            float s = 0.f, ss = 0.f;
            #pragma unroll
            for (int j = 0; j < 4; ++j) {
                const unsigned short* e = (const unsigned short*)&ch[j];
                #pragma unroll
                for (int b8 = 0; b8 < 8; ++b8) { float x = bf2f(e[b8]); s += x; ss += x * x; }
            }
            s += __shfl_xor(s, 1); ss += __shfl_xor(ss, 1);
            s += __shfl_xor(s, 2); ss += __shfl_xor(ss, 2);
            float mu = s * (1.f / 128.f);
            float var = ss * (1.f / 128.f) - mu * mu;
            float rstd = rsqrtf(var + 1e-5f);
            #pragma unroll
            for (int j = 0; j < 4; ++j) {
                int cj = (j + rr + ks) & 3;
                const unsigned short* e = (const unsigned short*)&ch[j];
                unsigned int dw[4];
                #pragma unroll
                for (int i = 0; i < 4; ++i) {
                    int p0 = cj * 8 + 2 * i, p1 = p0 + 1;
                    float x0 = (bf2f(e[2 * i])     - mu) * rstd * gP[ks * 32 + p0] + bP[ks * 32 + p0];
                    float x1 = (bf2f(e[2 * i + 1]) - mu) * rstd * gP[ks * 32 + p1] + bP[ks * 32 + p1];
                    dw[i] = packbf(x0, x1);
                }
                uint4 o; o.x = dw[0]; o.y = dw[1]; o.z = dw[2]; o.w = dw[3];
                xlnU4[baseq + cj] = o;
            }
        }
    }
    // no barrier: wave wv LN'd exactly rows [16wv,16wv+16) of BOTH groups and
    // reads only those below (same-wave LDS ops are in-order).

    const int wv = tid >> 6, l = tid & 63, lr = l & 15, lg = l >> 4;
    const uint4* wsq = (const uint4*)ws;

    FragU xf0[4], xf1[4];
    #pragma unroll
    for (int ks = 0; ks < 4; ++ks) {
        xf0[ks].u = xlnU4[ks * 256 + (wv * 16 + lr) * 4 + lg];
        xf1[ks].u = xlnU4[1024 + ks * 256 + (wv * 16 + lr) * 4 + lg];
    }

    const bool valid = ((lg >> 1) == (lr >> 3));     // same-pixel (q,k) pairs
    FragU pa0[4], pa1[4];
    #pragma unroll
    for (int ks = 0; ks < 4; ++ks) {
        pa0[ks].u.x = 0; pa0[ks].u.y = 0; pa0[ks].u.z = 0; pa0[ks].u.w = 0;
        pa1[ks].u.x = 0; pa1[ks].u.y = 0; pa1[ks].u.z = 0; pa1[ks].u.w = 0;
    }

    // ---- per-head: weights loaded once, used for both 64-row groups ----
    #pragma unroll
    for (int hd = 0; hd < 8; ++hd) {
        uint4 qa[4], ka[4], va[4];
        #pragma unroll
        for (int ks = 0; ks < 4; ++ks) {
            qa[ks] = wsq[((hd * 2 + 0) * 4 + ks) * 64 + l];
            ka[ks] = wsq[((hd * 2 + 1) * 4 + ks) * 64 + l];
            va[ks] = wsq[4096 + (hd * 4 + ks) * 64 + l];
        }
        f32x4 q0 = {0,0,0,0}, k0 = {0,0,0,0}, v0 = {0,0,0,0};
        f32x4 q1 = {0,0,0,0}, k1 = {0,0,0,0}, v1 = {0,0,0,0};
        #pragma unroll
        for (int ks = 0; ks < 4; ++ks) {
            FragU A, B, V2; A.u = qa[ks]; B.u = ka[ks]; V2.u = va[ks];
            q0 = __builtin_amdgcn_mfma_f32_16x16x32_bf16(A.v,  xf0[ks].v, q0, 0, 0, 0);
            k0 = __builtin_amdgcn_mfma_f32_16x16x32_bf16(B.v,  xf0[ks].v, k0, 0, 0, 0);
            q1 = __builtin_amdgcn_mfma_f32_16x16x32_bf16(A.v,  xf1[ks].v, q1, 0, 0, 0);
            k1 = __builtin_amdgcn_mfma_f32_16x16x32_bf16(B.v,  xf1[ks].v, k1, 0, 0, 0);
            v0 = __builtin_amdgcn_mfma_f32_16x16x32_bf16(xf0[ks].v, V2.v, v0, 0, 0, 0);
            v1 = __builtin_amdgcn_mfma_f32_16x16x32_bf16(xf1[ks].v, V2.v, v1, 0, 0, 0);
        }
        f32x4 o0 = attn_ov(q0, k0, v0, valid);
        f32x4 o1 = attn_ov(q1, k1, v1, valid);
        if ((hd & 1) == 0) {
            pa0[hd >> 1].u.x = packbf(o0.x, o0.y); pa0[hd >> 1].u.y = packbf(o0.z, o0.w);
            pa1[hd >> 1].u.x = packbf(o1.x, o1.y); pa1[hd >> 1].u.y = packbf(o1.z, o1.w);
        } else {
            pa0[hd >> 1].u.z = packbf(o0.x, o0.y); pa0[hd >> 1].u.w = packbf(o0.z, o0.w);
            pa1[hd >> 1].u.z = packbf(o1.x, o1.y); pa1[hd >> 1].u.w = packbf(o1.z, o1.w);
        }
    }

    // ---- proj GEMM: B-frags loaded once, used for both groups ----
    f32x4 pacc0[8], pacc1[8];
    #pragma unroll
    for (int nt = 0; nt < 8; ++nt) { pacc0[nt] = (f32x4){0,0,0,0}; pacc1[nt] = (f32x4){0,0,0,0}; }
    #pragma unroll
    for (int nt = 0; nt < 8; ++nt) {
        #pragma unroll
        for (int ks = 0; ks < 4; ++ks) {
            FragU B; B.u = wsq[6144 + (nt * 4 + ks) * 64 + l];
            pacc0[nt] = __builtin_amdgcn_mfma_f32_16x16x32_bf16(pa0[ks].v, B.v, pacc0[nt], 0, 0, 0);
            pacc1[nt] = __builtin_amdgcn_mfma_f32_16x16x32_bf16(pa1[ks].v, B.v, pacc1[nt], 0, 0, 0);
        }
    }

    __syncthreads();                                 // xln dead -> reuse as out_t
    // ---- epilogue: bias, XOR-swizzled transpose, residual, store ----
    unsigned short* out_t = xln16;                   // [g][n][col^n][pix]
    #pragma unroll
    for (int nt = 0; nt < 8; ++nt) {
        int col = nt * 16 + lr;
        float bias = bproj[col];
        #pragma unroll
        for (int j = 0; j < 4; ++j) {
            int row = wv * 16 + lg * 4 + j;          // row = pix_in_group*8 + n
            int n = row & 7, p = row >> 3;
            out_t[n * 1024 + (col ^ n) * 8 + p]        = f2bf(pacc0[nt][j] + bias);
            out_t[8192 + n * 1024 + (col ^ n) * 8 + p] = f2bf(pacc1[nt][j] + bias);
        }
    }
    __syncthreads();
    for (int it = 0; it < 4; ++it) {
        int t = it * 256 + tid;                      // 0..1023: g, cp, n
        int g = t & 1, cp = (t >> 1) & 63, n = t >> 7;
        int c = cp * 2;
        int gaddr = base + (n * CDIM + c) * HWSZ + g * 8;
        const float* rs = feat + gaddr;
        float4 r00 = *(const float4*)rs;
        float4 r01 = *(const float4*)(rs + 4);
        float4 r10 = *(const float4*)(rs + HWSZ);
        float4 r11 = *(const float4*)(rs + HWSZ + 4);
        uint4 tvA = *(const uint4*)(out_t + g * 8192 + n * 1024 + ((c    ) ^ n) * 8);
        uint4 tvB = *(const uint4*)(out_t + g * 8192 + n * 1024 + ((c + 1) ^ n) * 8);
        const unsigned short* tA = (const unsigned short*)&tvA;
        const unsigned short* tB = (const unsigned short*)&tvB;
        float4 o0, o1, o2, o3;
        o0.x = r00.x + bf2f(tA[0]); o0.y = r00.y + bf2f(tA[1]);
        o0.z = r00.z + bf2f(tA[2]); o0.w = r00.w + bf2f(tA[3]);
        o1.x = r01.x + bf2f(tA[4]); o1.y = r01.y + bf2f(tA[5]);
        o1.z = r01.z + bf2f(tA[6]); o1.w = r01.w + bf2f(tA[7]);
        o2.x = r10.x + bf2f(tB[0]); o2.y = r10.y + bf2f(tB[1]);
        o2.z = r10.z + bf2f(tB[2]); o2.w = r10.w + bf2f(tB[3]);
        o3.x = r11.x + bf2f(tB[4]); o3.y = r11.y + bf2f(tB[5]);
        o3.z = r11.z + bf2f(tB[6]); o3.w = r11.w + bf2f(tB[7]);
        *(float4*)(outp + gaddr)            = o0;
        *(float4*)(outp + gaddr + 4)        = o1;
        *(float4*)(outp + gaddr + HWSZ)     = o2;
        *(float4*)(outp + gaddr + HWSZ + 4) = o3;
    }
}

extern "C" void kernel_launch(void* const* d_in, const int* in_sizes, int n_in,
                              void* d_out, int out_size, void* d_ws, size_t ws_size,
                              hipStream_t stream) {
    const float* feat  = (const float*)d_in[0];
    const float* wqkv  = (const float*)d_in[1];
    const float* wproj = (const float*)d_in[2];
    const float* bproj = (const float*)d_in[3];
    const float* gamma = (const float*)d_in[4];
    const float* beta  = (const float*)d_in[5];
    unsigned short* ws = (unsigned short*)d_ws;      // needs 132096 B
    float* outp = (float*)d_out;

    hipLaunchKernelGGL(repack_k, dim3(33), dim3(256), 0, stream,
                       wqkv, wproj, gamma, beta, ws);
    hipLaunchKernelGGL(cfa_main, dim3(NBLK), dim3(256), 0, stream,
                       feat, bproj, ws, outp);
}

// Round 8
// 159.128 us; speedup vs baseline: 2.6545x; 1.0601x over previous
//
#include <hip/hip_runtime.h>

#define NFR 8
#define CDIM 128
#define HH 96
#define WW 96
#define NB 4
#define HWSZ 9216        // HH*WW
#define NBLK 2304        // NB*HH*(WW/16)
#define NXCD 8
#define CPX (NBLK / NXCD)  // 288

typedef __attribute__((ext_vector_type(8))) short bf16x8;
typedef __attribute__((ext_vector_type(4))) float f32x4;
typedef __attribute__((ext_vector_type(2))) float f32x2;
typedef __attribute__((ext_vector_type(2))) __bf16 bf16x2;

union FragU { uint4 u; bf16x8 v; };

__device__ inline float bf2f(unsigned short h) {
    unsigned int x = ((unsigned int)h) << 16;
    float f; __builtin_memcpy(&f, &x, 4); return f;
}
__device__ inline unsigned short f2bf(float f) {
    unsigned int x; __builtin_memcpy(&x, &f, 4);
    return (unsigned short)((x + 0x7FFFu + ((x >> 16) & 1u)) >> 16);
}
__device__ inline unsigned int packbf(float a, float b) {
    return (unsigned int)f2bf(a) | ((unsigned int)f2bf(b) << 16);
}
// HW path: compiler emits v_cvt_pk_bf16_f32 (RNE, same results as packbf)
__device__ inline unsigned int cvt2(float a, float b) {
    f32x2 f = {a, b};
    bf16x2 h = __builtin_convertvector(f, bf16x2);
    unsigned int u; __builtin_memcpy(&u, &h, 4); return u;
}
__device__ inline unsigned short cvt1(float a) {
    __bf16 h = (__bf16)a;
    unsigned short s; __builtin_memcpy(&s, &h, 2); return s;
}

// ---------------------------------------------------------------------------
// ws layout (uint4 units of 16B):
//   [0,    4096) : qk A-frags   ((hd*2+three)*4+ks)*64 + lane   (three: 0=q,1=k)
//                  q fragments pre-scaled by 0.25 (attention SCALE folded in)
//   [4096, 6144) : v  B-frags   (hd*4+ks)*64 + lane
//   [6144, 8192) : proj B-frags (nt*4+ks)*64 + lane
// bytes 131072: gammaP f32[128]; 131584: betaP f32[128]   (total 132096 B)
// Fragment element e (0..7) of (ks): channel c = ks*32 + lg*4 + (e&3) + ((e>>2)<<4)
// ---------------------------------------------------------------------------
__global__ __launch_bounds__(256)
void repack_k(const float* __restrict__ wqkv, const float* __restrict__ wproj,
              const float* __restrict__ gamma, const float* __restrict__ beta,
              unsigned short* __restrict__ ws)
{
    int gid = blockIdx.x * 256 + threadIdx.x;
    uint4* wsq = (uint4*)ws;
    int l = gid & 63, lr = l & 15, lg = (l >> 4) & 3;
    if (gid < 8192) {
        int unit = gid >> 6;
        int col, ks, stride;
        float scale = 1.0f;
        const float* src;
        if (unit < 64) {              // qk A-frags: A[m=col][k=c] = wqkv[c][col]
            int t = unit >> 2; ks = unit & 3;
            int hd = t >> 1, three = t & 1;
            col = three * 128 + hd * 16 + lr;
            src = wqkv; stride = 384;
            if (three == 0) scale = 0.25f;   // fold SCALE into q
        } else if (unit < 96) {       // v B-frags: B[k=c][n] = wqkv[c][256+hd*16+n]
            int u2 = unit - 64; int hd = u2 >> 2; ks = u2 & 3;
            col = 256 + hd * 16 + lr;
            src = wqkv; stride = 384;
        } else {                      // proj B-frags: B[k=c][n] = wproj[c][n]
            int u3 = unit - 96; int nt = u3 >> 2; ks = u3 & 3;
            col = nt * 16 + lr;
            src = wproj; stride = 128;
        }
        unsigned int dw[4];
        #pragma unroll
        for (int i = 0; i < 4; ++i) {
            int e0 = 2 * i, e1 = 2 * i + 1;
            int c0 = ks * 32 + lg * 4 + (e0 & 3) + ((e0 >> 2) << 4);
            int c1 = ks * 32 + lg * 4 + (e1 & 3) + ((e1 >> 2) << 4);
            dw[i] = packbf(src[c0 * stride + col] * scale, src[c1 * stride + col] * scale);
        }
        uint4 o; o.x = dw[0]; o.y = dw[1]; o.z = dw[2]; o.w = dw[3];
        wsq[gid] = o;
    } else if (gid < 8192 + 256) {
        int p = gid - 8192;           // 0..127 gamma, 128..255 beta (permuted)
        int pp = p & 127;
        int ks = pp >> 5, pos = pp & 31;
        int c = ks * 32 + ((pos >> 3) << 2) + (pos & 3) + (((pos >> 2) & 1) << 4);
        ((float*)ws)[32768 + p] = (p < 128) ? gamma[c] : beta[c];
    }
}

// all-register attention for one head, one 64-row group (SCALE pre-folded)
__device__ inline f32x4 attn_ov(f32x4 q, f32x4 k, f32x4 v, bool valid) {
    FragU qb, kb, vb;
    qb.u.x = cvt2(q.x, q.y); qb.u.y = cvt2(q.z, q.w); qb.u.z = 0; qb.u.w = 0;
    kb.u.x = cvt2(k.x, k.y); kb.u.y = cvt2(k.z, k.w); kb.u.z = 0; kb.u.w = 0;
    vb.u.x = cvt2(v.x, v.y); vb.u.y = cvt2(v.z, v.w); vb.u.z = 0; vb.u.w = 0;
    f32x4 zz = {0,0,0,0};
    // S^T = K·Q^T (K=16, upper half zero): lane holds S[q=lr][k=lg*4+j]
    f32x4 st = __builtin_amdgcn_mfma_f32_16x16x32_bf16(kb.v, qb.v, zz, 0, 0, 0);
    float sc0 = st.x, sc1 = st.y, sc2 = st.z, sc3 = st.w;
    float m = valid ? fmaxf(fmaxf(sc0, sc1), fmaxf(sc2, sc3)) : -3.0e38f;
    m = fmaxf(m, __shfl_xor(m, 16));
    float e0 = valid ? __expf(sc0 - m) : 0.f, e1 = valid ? __expf(sc1 - m) : 0.f;
    float e2 = valid ? __expf(sc2 - m) : 0.f, e3 = valid ? __expf(sc3 - m) : 0.f;
    float sm = e0 + e1 + e2 + e3; sm += __shfl_xor(sm, 16);
    float inv = 1.f / sm;
    FragU pb;
    pb.u.x = cvt2(valid ? e0 * inv : 0.f, valid ? e1 * inv : 0.f);
    pb.u.y = cvt2(valid ? e2 * inv : 0.f, valid ? e3 * inv : 0.f);
    pb.u.z = 0; pb.u.w = 0;
    // O^T = V^T·P^T: lane holds O[q=lr][d=lg*4+j]
    return __builtin_amdgcn_mfma_f32_16x16x32_bf16(vb.v, pb.v, zz, 0, 0, 0);
}

// ---------------------------------------------------------------------------
// xln LDS: two 16KB groups (pixels 0-7, 8-15). Within a group, u16 index =
// ks*2048 + row*32 + pos (row = pix_in_group*8 + n; pos = frag permutation of
// c&31) so each lane's MFMA fragment is one aligned ds_read_b128 and a wave
// tiles 1024B regions.
// ---------------------------------------------------------------------------
__global__ __launch_bounds__(256)
void cfa_main(const float* __restrict__ feat, const float* __restrict__ bproj,
              const unsigned short* __restrict__ ws, float* __restrict__ outp)
{
    __shared__ uint4 xlnU4[2048];                    // 32 KB
    unsigned short* xln16 = (unsigned short*)xlnU4;

    const int tid = threadIdx.x;
    const int blk = (int)(blockIdx.x % NXCD) * CPX + (int)blockIdx.x / NXCD;
    const int wt = blk % 6, h = (blk / 6) % 96, b = blk / (6 * 96);
    const int base = ((b * NFR) * CDIM) * HWSZ + h * WW + wt * 16;

    // ---- phase 1: stage 16 pixels; 8 channels/thread -> ds_write_b128 ----
    // thread = (g, ks, n, q): loads channels ks*32+q*4+{0..3,16..19}, 8 pixels
    // of frame n (pixel half g), writes one 16B fragment chunk per pixel.
    {
        int g = tid >> 7, rem = tid & 127;
        int ks = rem >> 5, n = (rem >> 2) & 7, q = rem & 3;
        const float* fb = feat + base + n * CDIM * HWSZ + g * 8;
        int c0 = ks * 32 + q * 4;
        #pragma unroll
        for (int hf = 0; hf < 2; ++hf) {             // pixel sub-half (4 pixels)
            float4 L[2][4];
            #pragma unroll
            for (int hi = 0; hi < 2; ++hi)
                #pragma unroll
                for (int dj = 0; dj < 4; ++dj)
                    L[hi][dj] = *(const float4*)(fb + (c0 + dj + hi * 16) * HWSZ + hf * 4);
            #pragma unroll
            for (int pp = 0; pp < 4; ++pp) {
                int p = hf * 4 + pp;
                const float* l00 = (const float*)&L[0][0];
                const float* l01 = (const float*)&L[0][1];
                const float* l02 = (const float*)&L[0][2];
                const float* l03 = (const float*)&L[0][3];
                const float* l10 = (const float*)&L[1][0];
                const float* l11 = (const float*)&L[1][1];
                const float* l12 = (const float*)&L[1][2];
                const float* l13 = (const float*)&L[1][3];
                uint4 w;
                w.x = cvt2(l00[pp], l01[pp]);
                w.y = cvt2(l02[pp], l03[pp]);
                w.z = cvt2(l10[pp], l11[pp]);
                w.w = cvt2(l12[pp], l13[pp]);
                xlnU4[g * 1024 + ks * 256 + (p * 8 + n) * 4 + q] = w;
            }
        }
    }
    __syncthreads();

    // ---- phase 2: LayerNorm in-place, both groups ----
    {
        const float* gP = (const float*)ws + 32768;
        const float* bP = gP + 128;
        int rr = tid >> 2, ks = tid & 3;
        #pragma unroll
        for (int g = 0; g < 2; ++g) {
            int baseq = g * 1024 + ks * 256 + rr * 4;
            uint4 ch[4];
            #pragma unroll
            for (int j = 0; j < 4; ++j) ch[j] = xlnU4[baseq + ((j + rr + ks) & 3)];
            float s = 0.f, ss = 0.f;
            #pragma unroll
            for (int j = 0; j < 4; ++j) {
                const unsigned short* e = (const unsigned short*)&ch[j];
                #pragma unroll
                for (int b8 = 0; b8 < 8; ++b8) { float x = bf2f(e[b8]); s += x; ss += x * x; }
            }
            s += __shfl_xor(s, 1); ss += __shfl_xor(ss, 1);
            s += __shfl_xor(s, 2); ss += __shfl_xor(ss, 2);
            float mu = s * (1.f / 128.f);
            float var = ss * (1.f / 128.f) - mu * mu;
            float rstd = rsqrtf(var + 1e-5f);
            #pragma unroll
            for (int j = 0; j < 4; ++j) {
                int cj = (j + rr + ks) & 3;
                const unsigned short* e = (const unsigned short*)&ch[j];
                unsigned int dw[4];
                #pragma unroll
                for (int i = 0; i < 4; ++i) {
                    int p0 = cj * 8 + 2 * i, p1 = p0 + 1;
                    float x0 = (bf2f(e[2 * i])     - mu) * rstd * gP[ks * 32 + p0] + bP[ks * 32 + p0];
                    float x1 = (bf2f(e[2 * i + 1]) - mu) * rstd * gP[ks * 32 + p1] + bP[ks * 32 + p1];
                    dw[i] = cvt2(x0, x1);
                }
                uint4 o; o.x = dw[0]; o.y = dw[1]; o.z = dw[2]; o.w = dw[3];
                xlnU4[baseq + cj] = o;
            }
        }
    }
    // no barrier: wave wv LN'd exactly rows [16wv,16wv+16) of BOTH groups and
    // reads only those below (same-wave LDS ops are in-order).

    const int wv = tid >> 6, l = tid & 63, lr = l & 15, lg = l >> 4;
    const uint4* wsq = (const uint4*)ws;

    FragU xf0[4], xf1[4];
    #pragma unroll
    for (int ks = 0; ks < 4; ++ks) {
        xf0[ks].u = xlnU4[ks * 256 + (wv * 16 + lr) * 4 + lg];
        xf1[ks].u = xlnU4[1024 + ks * 256 + (wv * 16 + lr) * 4 + lg];
    }

    const bool valid = ((lg >> 1) == (lr >> 3));     // same-pixel (q,k) pairs
    FragU pa0[4], pa1[4];
    #pragma unroll
    for (int ks = 0; ks < 4; ++ks) {
        pa0[ks].u.x = 0; pa0[ks].u.y = 0; pa0[ks].u.z = 0; pa0[ks].u.w = 0;
        pa1[ks].u.x = 0; pa1[ks].u.y = 0; pa1[ks].u.z = 0; pa1[ks].u.w = 0;
    }

    // ---- per-head: weights loaded once, used for both 64-row groups ----
    #pragma unroll
    for (int hd = 0; hd < 8; ++hd) {
        uint4 qa[4], ka[4], va[4];
        #pragma unroll
        for (int ks = 0; ks < 4; ++ks) {
            qa[ks] = wsq[((hd * 2 + 0) * 4 + ks) * 64 + l];
            ka[ks] = wsq[((hd * 2 + 1) * 4 + ks) * 64 + l];
            va[ks] = wsq[4096 + (hd * 4 + ks) * 64 + l];
        }
        f32x4 q0 = {0,0,0,0}, k0 = {0,0,0,0}, v0 = {0,0,0,0};
        f32x4 q1 = {0,0,0,0}, k1 = {0,0,0,0}, v1 = {0,0,0,0};
        #pragma unroll
        for (int ks = 0; ks < 4; ++ks) {
            FragU A, B, V2; A.u = qa[ks]; B.u = ka[ks]; V2.u = va[ks];
            q0 = __builtin_amdgcn_mfma_f32_16x16x32_bf16(A.v,  xf0[ks].v, q0, 0, 0, 0);
            k0 = __builtin_amdgcn_mfma_f32_16x16x32_bf16(B.v,  xf0[ks].v, k0, 0, 0, 0);
            q1 = __builtin_amdgcn_mfma_f32_16x16x32_bf16(A.v,  xf1[ks].v, q1, 0, 0, 0);
            k1 = __builtin_amdgcn_mfma_f32_16x16x32_bf16(B.v,  xf1[ks].v, k1, 0, 0, 0);
            v0 = __builtin_amdgcn_mfma_f32_16x16x32_bf16(xf0[ks].v, V2.v, v0, 0, 0, 0);
            v1 = __builtin_amdgcn_mfma_f32_16x16x32_bf16(xf1[ks].v, V2.v, v1, 0, 0, 0);
        }
        f32x4 o0 = attn_ov(q0, k0, v0, valid);
        f32x4 o1 = attn_ov(q1, k1, v1, valid);
        if ((hd & 1) == 0) {
            pa0[hd >> 1].u.x = cvt2(o0.x, o0.y); pa0[hd >> 1].u.y = cvt2(o0.z, o0.w);
            pa1[hd >> 1].u.x = cvt2(o1.x, o1.y); pa1[hd >> 1].u.y = cvt2(o1.z, o1.w);
        } else {
            pa0[hd >> 1].u.z = cvt2(o0.x, o0.y); pa0[hd >> 1].u.w = cvt2(o0.z, o0.w);
            pa1[hd >> 1].u.z = cvt2(o1.x, o1.y); pa1[hd >> 1].u.w = cvt2(o1.z, o1.w);
        }
    }

    // ---- proj GEMM: B-frags loaded once, used for both groups ----
    f32x4 pacc0[8], pacc1[8];
    #pragma unroll
    for (int nt = 0; nt < 8; ++nt) { pacc0[nt] = (f32x4){0,0,0,0}; pacc1[nt] = (f32x4){0,0,0,0}; }
    #pragma unroll
    for (int nt = 0; nt < 8; ++nt) {
        #pragma unroll
        for (int ks = 0; ks < 4; ++ks) {
            FragU B; B.u = wsq[6144 + (nt * 4 + ks) * 64 + l];
            pacc0[nt] = __builtin_amdgcn_mfma_f32_16x16x32_bf16(pa0[ks].v, B.v, pacc0[nt], 0, 0, 0);
            pacc1[nt] = __builtin_amdgcn_mfma_f32_16x16x32_bf16(pa1[ks].v, B.v, pacc1[nt], 0, 0, 0);
        }
    }

    __syncthreads();                                 // xln dead -> reuse as out_t
    // ---- epilogue: bias, XOR-swizzled transpose, residual, store ----
    unsigned short* out_t = xln16;                   // [g][n][col^n][pix]
    #pragma unroll
    for (int nt = 0; nt < 8; ++nt) {
        int col = nt * 16 + lr;
        float bias = bproj[col];
        #pragma unroll
        for (int j = 0; j < 4; ++j) {
            int row = wv * 16 + lg * 4 + j;          // row = pix_in_group*8 + n
            int n = row & 7, p = row >> 3;
            out_t[n * 1024 + (col ^ n) * 8 + p]        = cvt1(pacc0[nt][j] + bias);
            out_t[8192 + n * 1024 + (col ^ n) * 8 + p] = cvt1(pacc1[nt][j] + bias);
        }
    }
    __syncthreads();
    for (int it = 0; it < 4; ++it) {
        int t = it * 256 + tid;                      // 0..1023: g, cp, n
        int g = t & 1, cp = (t >> 1) & 63, n = t >> 7;
        int c = cp * 2;
        int gaddr = base + (n * CDIM + c) * HWSZ + g * 8;
        const float* rs = feat + gaddr;
        float4 r00 = *(const float4*)rs;
        float4 r01 = *(const float4*)(rs + 4);
        float4 r10 = *(const float4*)(rs + HWSZ);
        float4 r11 = *(const float4*)(rs + HWSZ + 4);
        uint4 tvA = *(const uint4*)(out_t + g * 8192 + n * 1024 + ((c    ) ^ n) * 8);
        uint4 tvB = *(const uint4*)(out_t + g * 8192 + n * 1024 + ((c + 1) ^ n) * 8);
        const unsigned short* tA = (const unsigned short*)&tvA;
        const unsigned short* tB = (const unsigned short*)&tvB;
        float4 o0, o1, o2, o3;
        o0.x = r00.x + bf2f(tA[0]); o0.y = r00.y + bf2f(tA[1]);
        o0.z = r00.z + bf2f(tA[2]); o0.w = r00.w + bf2f(tA[3]);
        o1.x = r01.x + bf2f(tA[4]); o1.y = r01.y + bf2f(tA[5]);
        o1.z = r01.z + bf2f(tA[6]); o1.w = r01.w + bf2f(tA[7]);
        o2.x = r10.x + bf2f(tB[0]); o2.y = r10.y + bf2f(tB[1]);
        o2.z = r10.z + bf2f(tB[2]); o2.w = r10.w + bf2f(tB[3]);
        o3.x = r11.x + bf2f(tB[4]); o3.y = r11.y + bf2f(tB[5]);
        o3.z = r11.z + bf2f(tB[6]); o3.w = r11.w + bf2f(tB[7]);
        *(float4*)(outp + gaddr)            = o0;
        *(float4*)(outp + gaddr + 4)        = o1;
        *(float4*)(outp + gaddr + HWSZ)     = o2;
        *(float4*)(outp + gaddr + HWSZ + 4) = o3;
    }
}

extern "C" void kernel_launch(void* const* d_in, const int* in_sizes, int n_in,
                              void* d_out, int out_size, void* d_ws, size_t ws_size,
                              hipStream_t stream) {
    const float* feat  = (const float*)d_in[0];
    const float* wqkv  = (const float*)d_in[1];
    const float* wproj = (const float*)d_in[2];
    const float* bproj = (const float*)d_in[3];
    const float* gamma = (const float*)d_in[4];
    const float* beta  = (const float*)d_in[5];
    unsigned short* ws = (unsigned short*)d_ws;      // needs 132096 B
    float* outp = (float*)d_out;

    hipLaunchKernelGGL(repack_k, dim3(33), dim3(256), 0, stream,
                       wqkv, wproj, gamma, beta, ws);
    hipLaunchKernelGGL(cfa_main, dim3(NBLK), dim3(256), 0, stream,
                       feat, bproj, ws, outp);
}

// Round 9
// 148.915 us; speedup vs baseline: 2.8366x; 1.0686x over previous
//
#include <hip/hip_runtime.h>

#define NFR 8
#define CDIM 128
#define HH 96
#define WW 96
#define NB 4
#define HWSZ 9216        // HH*WW
#define NBLK 2304        // NB*HH*(WW/16)
#define NXCD 8
#define CPX (NBLK / NXCD)  // 288

typedef __attribute__((ext_vector_type(8))) short bf16x8;
typedef __attribute__((ext_vector_type(4))) float f32x4;
typedef __attribute__((ext_vector_type(2))) float f32x2;
typedef __attribute__((ext_vector_type(2))) __bf16 bf16x2;

union FragU { uint4 u; bf16x8 v; };

__device__ inline float bf2f(unsigned short h) {
    unsigned int x = ((unsigned int)h) << 16;
    float f; __builtin_memcpy(&f, &x, 4); return f;
}
__device__ inline unsigned short f2bf(float f) {
    unsigned int x; __builtin_memcpy(&x, &f, 4);
    return (unsigned short)((x + 0x7FFFu + ((x >> 16) & 1u)) >> 16);
}
__device__ inline unsigned int packbf(float a, float b) {
    return (unsigned int)f2bf(a) | ((unsigned int)f2bf(b) << 16);
}
// HW path: compiler emits v_cvt_pk_bf16_f32 (RNE, same results as packbf)
__device__ inline unsigned int cvt2(float a, float b) {
    f32x2 f = {a, b};
    bf16x2 h = __builtin_convertvector(f, bf16x2);
    unsigned int u; __builtin_memcpy(&u, &h, 4); return u;
}
__device__ inline unsigned short cvt1(float a) {
    __bf16 h = (__bf16)a;
    unsigned short s; __builtin_memcpy(&s, &h, 2); return s;
}

// ---------------------------------------------------------------------------
// ws layout (uint4 units of 16B):
//   [0,    4096) : qk A-frags   ((hd*2+three)*4+ks)*64 + lane   (three: 0=q,1=k)
//                  q fragments pre-scaled by 0.25 (attention SCALE folded in)
//   [4096, 6144) : v  B-frags   (hd*4+ks)*64 + lane
//   [6144, 8192) : proj B-frags (nt*4+ks)*64 + lane
// bytes 131072: gammaP f32[128]; 131584: betaP f32[128]   (total 132096 B)
// Fragment element e (0..7) of (ks): channel c = ks*32 + lg*4 + (e&3) + ((e>>2)<<4)
// ---------------------------------------------------------------------------
__global__ __launch_bounds__(256)
void repack_k(const float* __restrict__ wqkv, const float* __restrict__ wproj,
              const float* __restrict__ gamma, const float* __restrict__ beta,
              unsigned short* __restrict__ ws)
{
    int gid = blockIdx.x * 256 + threadIdx.x;
    uint4* wsq = (uint4*)ws;
    int l = gid & 63, lr = l & 15, lg = (l >> 4) & 3;
    if (gid < 8192) {
        int unit = gid >> 6;
        int col, ks, stride;
        float scale = 1.0f;
        const float* src;
        if (unit < 64) {              // qk A-frags: A[m=col][k=c] = wqkv[c][col]
            int t = unit >> 2; ks = unit & 3;
            int hd = t >> 1, three = t & 1;
            col = three * 128 + hd * 16 + lr;
            src = wqkv; stride = 384;
            if (three == 0) scale = 0.25f;   // fold SCALE into q
        } else if (unit < 96) {       // v B-frags: B[k=c][n] = wqkv[c][256+hd*16+n]
            int u2 = unit - 64; int hd = u2 >> 2; ks = u2 & 3;
            col = 256 + hd * 16 + lr;
            src = wqkv; stride = 384;
        } else {                      // proj B-frags: B[k=c][n] = wproj[c][n]
            int u3 = unit - 96; int nt = u3 >> 2; ks = u3 & 3;
            col = nt * 16 + lr;
            src = wproj; stride = 128;
        }
        unsigned int dw[4];
        #pragma unroll
        for (int i = 0; i < 4; ++i) {
            int e0 = 2 * i, e1 = 2 * i + 1;
            int c0 = ks * 32 + lg * 4 + (e0 & 3) + ((e0 >> 2) << 4);
            int c1 = ks * 32 + lg * 4 + (e1 & 3) + ((e1 >> 2) << 4);
            dw[i] = packbf(src[c0 * stride + col] * scale, src[c1 * stride + col] * scale);
        }
        uint4 o; o.x = dw[0]; o.y = dw[1]; o.z = dw[2]; o.w = dw[3];
        wsq[gid] = o;
    } else if (gid < 8192 + 256) {
        int p = gid - 8192;           // 0..127 gamma, 128..255 beta (permuted)
        int pp = p & 127;
        int ks = pp >> 5, pos = pp & 31;
        int c = ks * 32 + ((pos >> 3) << 2) + (pos & 3) + (((pos >> 2) & 1) << 4);
        ((float*)ws)[32768 + p] = (p < 128) ? gamma[c] : beta[c];
    }
}

// all-register attention for one head, one 64-row group (SCALE pre-folded)
__device__ inline f32x4 attn_ov(f32x4 q, f32x4 k, f32x4 v, bool valid) {
    FragU qb, kb, vb;
    qb.u.x = cvt2(q.x, q.y); qb.u.y = cvt2(q.z, q.w); qb.u.z = 0; qb.u.w = 0;
    kb.u.x = cvt2(k.x, k.y); kb.u.y = cvt2(k.z, k.w); kb.u.z = 0; kb.u.w = 0;
    vb.u.x = cvt2(v.x, v.y); vb.u.y = cvt2(v.z, v.w); vb.u.z = 0; vb.u.w = 0;
    f32x4 zz = {0,0,0,0};
    // S^T = K·Q^T (K=16, upper half zero): lane holds S[q=lr][k=lg*4+j]
    f32x4 st = __builtin_amdgcn_mfma_f32_16x16x32_bf16(kb.v, qb.v, zz, 0, 0, 0);
    float sc0 = st.x, sc1 = st.y, sc2 = st.z, sc3 = st.w;
    float m = valid ? fmaxf(fmaxf(sc0, sc1), fmaxf(sc2, sc3)) : -3.0e38f;
    m = fmaxf(m, __shfl_xor(m, 16));
    float e0 = valid ? __expf(sc0 - m) : 0.f, e1 = valid ? __expf(sc1 - m) : 0.f;
    float e2 = valid ? __expf(sc2 - m) : 0.f, e3 = valid ? __expf(sc3 - m) : 0.f;
    float sm = e0 + e1 + e2 + e3; sm += __shfl_xor(sm, 16);
    float inv = 1.f / sm;
    FragU pb;
    pb.u.x = cvt2(valid ? e0 * inv : 0.f, valid ? e1 * inv : 0.f);
    pb.u.y = cvt2(valid ? e2 * inv : 0.f, valid ? e3 * inv : 0.f);
    pb.u.z = 0; pb.u.w = 0;
    // O^T = V^T·P^T: lane holds O[q=lr][d=lg*4+j]
    return __builtin_amdgcn_mfma_f32_16x16x32_bf16(vb.v, pb.v, zz, 0, 0, 0);
}

// ---------------------------------------------------------------------------
// xln LDS: two 16KB groups (pixels 0-7, 8-15). Within a group, u16 index =
// ks*2048 + row*32 + pos (row = pix_in_group*8 + n; pos = frag permutation of
// c&31) so each lane's MFMA fragment is one aligned ds_read_b128 and a wave
// tiles 1024B regions.
// ---------------------------------------------------------------------------
__global__ __launch_bounds__(256, 3)
void cfa_main(const float* __restrict__ feat, const float* __restrict__ bproj,
              const unsigned short* __restrict__ ws, float* __restrict__ outp)
{
    __shared__ uint4 xlnU4[2048];                    // 32 KB
    unsigned short* xln16 = (unsigned short*)xlnU4;

    const int tid = threadIdx.x;
    const int blk = (int)(blockIdx.x % NXCD) * CPX + (int)blockIdx.x / NXCD;
    const int wt = blk % 6, h = (blk / 6) % 96, b = blk / (6 * 96);
    const int base = ((b * NFR) * CDIM) * HWSZ + h * WW + wt * 16;

    // ---- phase 1: stage 16 pixels; 8 channels/thread -> ds_write_b128 ----
    {
        int g = tid >> 7, rem = tid & 127;
        int ks = rem >> 5, n = (rem >> 2) & 7, q = rem & 3;
        const float* fb = feat + base + n * CDIM * HWSZ + g * 8;
        int c0 = ks * 32 + q * 4;
        #pragma unroll
        for (int hf = 0; hf < 2; ++hf) {             // pixel sub-half (4 pixels)
            float4 L[2][4];
            #pragma unroll
            for (int hi = 0; hi < 2; ++hi)
                #pragma unroll
                for (int dj = 0; dj < 4; ++dj)
                    L[hi][dj] = *(const float4*)(fb + (c0 + dj + hi * 16) * HWSZ + hf * 4);
            #pragma unroll
            for (int pp = 0; pp < 4; ++pp) {
                int p = hf * 4 + pp;
                const float* l00 = (const float*)&L[0][0];
                const float* l01 = (const float*)&L[0][1];
                const float* l02 = (const float*)&L[0][2];
                const float* l03 = (const float*)&L[0][3];
                const float* l10 = (const float*)&L[1][0];
                const float* l11 = (const float*)&L[1][1];
                const float* l12 = (const float*)&L[1][2];
                const float* l13 = (const float*)&L[1][3];
                uint4 w;
                w.x = cvt2(l00[pp], l01[pp]);
                w.y = cvt2(l02[pp], l03[pp]);
                w.z = cvt2(l10[pp], l11[pp]);
                w.w = cvt2(l12[pp], l13[pp]);
                xlnU4[g * 1024 + ks * 256 + (p * 8 + n) * 4 + q] = w;
            }
        }
    }
    __syncthreads();

    // ---- phase 2: LayerNorm in-place, both groups ----
    {
        const float* gP = (const float*)ws + 32768;
        const float* bP = gP + 128;
        int rr = tid >> 2, ks = tid & 3;
        #pragma unroll
        for (int g = 0; g < 2; ++g) {
            int baseq = g * 1024 + ks * 256 + rr * 4;
            uint4 ch[4];
            #pragma unroll
            for (int j = 0; j < 4; ++j) ch[j] = xlnU4[baseq + ((j + rr + ks) & 3)];
            float s = 0.f, ss = 0.f;
            #pragma unroll
            for (int j = 0; j < 4; ++j) {
                const unsigned short* e = (const unsigned short*)&ch[j];
                #pragma unroll
                for (int b8 = 0; b8 < 8; ++b8) { float x = bf2f(e[b8]); s += x; ss += x * x; }
            }
            s += __shfl_xor(s, 1); ss += __shfl_xor(ss, 1);
            s += __shfl_xor(s, 2); ss += __shfl_xor(ss, 2);
            float mu = s * (1.f / 128.f);
            float var = ss * (1.f / 128.f) - mu * mu;
            float rstd = rsqrtf(var + 1e-5f);
            #pragma unroll
            for (int j = 0; j < 4; ++j) {
                int cj = (j + rr + ks) & 3;
                const unsigned short* e = (const unsigned short*)&ch[j];
                unsigned int dw[4];
                #pragma unroll
                for (int i = 0; i < 4; ++i) {
                    int p0 = cj * 8 + 2 * i, p1 = p0 + 1;
                    float x0 = (bf2f(e[2 * i])     - mu) * rstd * gP[ks * 32 + p0] + bP[ks * 32 + p0];
                    float x1 = (bf2f(e[2 * i + 1]) - mu) * rstd * gP[ks * 32 + p1] + bP[ks * 32 + p1];
                    dw[i] = cvt2(x0, x1);
                }
                uint4 o; o.x = dw[0]; o.y = dw[1]; o.z = dw[2]; o.w = dw[3];
                xlnU4[baseq + cj] = o;
            }
        }
    }
    // no barrier: wave wv LN'd exactly rows [16wv,16wv+16) of BOTH groups and
    // reads only those below (same-wave LDS ops are in-order).

    const int wv = tid >> 6, l = tid & 63, lr = l & 15, lg = l >> 4;
    const uint4* wsq = (const uint4*)ws;

    FragU xf0[4], xf1[4];
    #pragma unroll
    for (int ks = 0; ks < 4; ++ks) {
        xf0[ks].u = xlnU4[ks * 256 + (wv * 16 + lr) * 4 + lg];
        xf1[ks].u = xlnU4[1024 + ks * 256 + (wv * 16 + lr) * 4 + lg];
    }
    __syncthreads();   // all waves have their xf fragments; xlnU4 is now free
                       // for out_t streaming (no xlnU4 reads after this point)

    const bool valid = ((lg >> 1) == (lr >> 3));     // same-pixel (q,k) pairs
    FragU pa0[4], pa1[4];
    #pragma unroll
    for (int ks = 0; ks < 4; ++ks) {
        pa0[ks].u.x = 0; pa0[ks].u.y = 0; pa0[ks].u.z = 0; pa0[ks].u.w = 0;
        pa1[ks].u.x = 0; pa1[ks].u.y = 0; pa1[ks].u.z = 0; pa1[ks].u.w = 0;
    }

    // ---- per-head: weights loaded in-loop (used once each), both groups ----
    #pragma unroll
    for (int hd = 0; hd < 8; ++hd) {
        f32x4 q0 = {0,0,0,0}, k0 = {0,0,0,0}, v0 = {0,0,0,0};
        f32x4 q1 = {0,0,0,0}, k1 = {0,0,0,0}, v1 = {0,0,0,0};
        #pragma unroll
        for (int ks = 0; ks < 4; ++ks) {
            FragU A, B, V2;
            A.u  = wsq[((hd * 2 + 0) * 4 + ks) * 64 + l];
            B.u  = wsq[((hd * 2 + 1) * 4 + ks) * 64 + l];
            V2.u = wsq[4096 + (hd * 4 + ks) * 64 + l];
            q0 = __builtin_amdgcn_mfma_f32_16x16x32_bf16(A.v,  xf0[ks].v, q0, 0, 0, 0);
            k0 = __builtin_amdgcn_mfma_f32_16x16x32_bf16(B.v,  xf0[ks].v, k0, 0, 0, 0);
            q1 = __builtin_amdgcn_mfma_f32_16x16x32_bf16(A.v,  xf1[ks].v, q1, 0, 0, 0);
            k1 = __builtin_amdgcn_mfma_f32_16x16x32_bf16(B.v,  xf1[ks].v, k1, 0, 0, 0);
            v0 = __builtin_amdgcn_mfma_f32_16x16x32_bf16(xf0[ks].v, V2.v, v0, 0, 0, 0);
            v1 = __builtin_amdgcn_mfma_f32_16x16x32_bf16(xf1[ks].v, V2.v, v1, 0, 0, 0);
        }
        f32x4 o0 = attn_ov(q0, k0, v0, valid);
        f32x4 o1 = attn_ov(q1, k1, v1, valid);
        if ((hd & 1) == 0) {
            pa0[hd >> 1].u.x = cvt2(o0.x, o0.y); pa0[hd >> 1].u.y = cvt2(o0.z, o0.w);
            pa1[hd >> 1].u.x = cvt2(o1.x, o1.y); pa1[hd >> 1].u.y = cvt2(o1.z, o1.w);
        } else {
            pa0[hd >> 1].u.z = cvt2(o0.x, o0.y); pa0[hd >> 1].u.w = cvt2(o0.z, o0.w);
            pa1[hd >> 1].u.z = cvt2(o1.x, o1.y); pa1[hd >> 1].u.w = cvt2(o1.z, o1.w);
        }
    }

    // ---- proj GEMM, streamed: per nt compute 2 accs and write to out_t ----
    unsigned short* out_t = xln16;                   // [g][n][col^n][pix]
    #pragma unroll
    for (int nt = 0; nt < 8; ++nt) {
        f32x4 a0 = {0,0,0,0}, a1 = {0,0,0,0};
        #pragma unroll
        for (int ks = 0; ks < 4; ++ks) {
            FragU B; B.u = wsq[6144 + (nt * 4 + ks) * 64 + l];
            a0 = __builtin_amdgcn_mfma_f32_16x16x32_bf16(pa0[ks].v, B.v, a0, 0, 0, 0);
            a1 = __builtin_amdgcn_mfma_f32_16x16x32_bf16(pa1[ks].v, B.v, a1, 0, 0, 0);
        }
        int col = nt * 16 + lr;
        float bias = bproj[col];
        #pragma unroll
        for (int j = 0; j < 4; ++j) {
            int row = wv * 16 + lg * 4 + j;          // row = pix_in_group*8 + n
            int n = row & 7, p = row >> 3;
            out_t[n * 1024 + (col ^ n) * 8 + p]        = cvt1(a0[j] + bias);
            out_t[8192 + n * 1024 + (col ^ n) * 8 + p] = cvt1(a1[j] + bias);
        }
    }
    __syncthreads();
    // ---- epilogue: residual re-read (L2-hot) + store ----
    for (int it = 0; it < 4; ++it) {
        int t = it * 256 + tid;                      // 0..1023: g, cp, n
        int g = t & 1, cp = (t >> 1) & 63, n = t >> 7;
        int c = cp * 2;
        int gaddr = base + (n * CDIM + c) * HWSZ + g * 8;
        const float* rs = feat + gaddr;
        float4 r00 = *(const float4*)rs;
        float4 r01 = *(const float4*)(rs + 4);
        float4 r10 = *(const float4*)(rs + HWSZ);
        float4 r11 = *(const float4*)(rs + HWSZ + 4);
        uint4 tvA = *(const uint4*)(out_t + g * 8192 + n * 1024 + ((c    ) ^ n) * 8);
        uint4 tvB = *(const uint4*)(out_t + g * 8192 + n * 1024 + ((c + 1) ^ n) * 8);
        const unsigned short* tA = (const unsigned short*)&tvA;
        const unsigned short* tB = (const unsigned short*)&tvB;
        float4 o0, o1, o2, o3;
        o0.x = r00.x + bf2f(tA[0]); o0.y = r00.y + bf2f(tA[1]);
        o0.z = r00.z + bf2f(tA[2]); o0.w = r00.w + bf2f(tA[3]);
        o1.x = r01.x + bf2f(tA[4]); o1.y = r01.y + bf2f(tA[5]);
        o1.z = r01.z + bf2f(tA[6]); o1.w = r01.w + bf2f(tA[7]);
        o2.x = r10.x + bf2f(tB[0]); o2.y = r10.y + bf2f(tB[1]);
        o2.z = r10.z + bf2f(tB[2]); o2.w = r10.w + bf2f(tB[3]);
        o3.x = r11.x + bf2f(tB[4]); o3.y = r11.y + bf2f(tB[5]);
        o3.z = r11.z + bf2f(tB[6]); o3.w = r11.w + bf2f(tB[7]);
        *(float4*)(outp + gaddr)            = o0;
        *(float4*)(outp + gaddr + 4)        = o1;
        *(float4*)(outp + gaddr + HWSZ)     = o2;
        *(float4*)(outp + gaddr + HWSZ + 4) = o3;
    }
}

extern "C" void kernel_launch(void* const* d_in, const int* in_sizes, int n_in,
                              void* d_out, int out_size, void* d_ws, size_t ws_size,
                              hipStream_t stream) {
    const float* feat  = (const float*)d_in[0];
    const float* wqkv  = (const float*)d_in[1];
    const float* wproj = (const float*)d_in[2];
    const float* bproj = (const float*)d_in[3];
    const float* gamma = (const float*)d_in[4];
    const float* beta  = (const float*)d_in[5];
    unsigned short* ws = (unsigned short*)d_ws;      // needs 132096 B
    float* outp = (float*)d_out;

    hipLaunchKernelGGL(repack_k, dim3(33), dim3(256), 0, stream,
                       wqkv, wproj, gamma, beta, ws);
    hipLaunchKernelGGL(cfa_main, dim3(NBLK), dim3(256), 0, stream,
                       feat, bproj, ws, outp);
}

// Round 10
// 128.071 us; speedup vs baseline: 3.2982x; 1.1628x over previous
//
#include <hip/hip_runtime.h>

#define NFR 8
#define CDIM 128
#define HH 96
#define WW 96
#define NB 4
#define HWSZ 9216        // HH*WW
#define NBLK 2304        // NB*HH*(WW/16)
#define NXCD 8
#define CPX (NBLK / NXCD)  // 288

typedef __attribute__((ext_vector_type(8))) short bf16x8;
typedef __attribute__((ext_vector_type(4))) float f32x4;
typedef __attribute__((ext_vector_type(2))) float f32x2;
typedef __attribute__((ext_vector_type(2))) __bf16 bf16x2;

union FragU { uint4 u; bf16x8 v; };

__device__ inline float bf2f(unsigned short h) {
    unsigned int x = ((unsigned int)h) << 16;
    float f; __builtin_memcpy(&f, &x, 4); return f;
}
__device__ inline unsigned short f2bf(float f) {
    unsigned int x; __builtin_memcpy(&x, &f, 4);
    return (unsigned short)((x + 0x7FFFu + ((x >> 16) & 1u)) >> 16);
}
__device__ inline unsigned int packbf(float a, float b) {
    return (unsigned int)f2bf(a) | ((unsigned int)f2bf(b) << 16);
}
// HW path: compiler emits v_cvt_pk_bf16_f32 (RNE, same results as packbf)
__device__ inline unsigned int cvt2(float a, float b) {
    f32x2 f = {a, b};
    bf16x2 h = __builtin_convertvector(f, bf16x2);
    unsigned int u; __builtin_memcpy(&u, &h, 4); return u;
}
__device__ inline unsigned short cvt1(float a) {
    __bf16 h = (__bf16)a;
    unsigned short s; __builtin_memcpy(&s, &h, 2); return s;
}
// fragment-permutation position of channel-within-32 (even for even c5)
__device__ inline int posmap(int c5) {
    return (c5 < 16) ? (((c5 >> 2) << 3) + (c5 & 3))
                     : ((((c5 & 15) >> 2) << 3) + 4 + (c5 & 3));
}

// ---------------------------------------------------------------------------
// ws layout (uint4 units of 16B):
//   [0,    4096) : qk A-frags   ((hd*2+three)*4+ks)*64 + lane   (three: 0=q,1=k)
//                  q fragments pre-scaled by 0.25 (attention SCALE folded in)
//   [4096, 6144) : v  B-frags   (hd*4+ks)*64 + lane
//   [6144, 8192) : proj B-frags (nt*4+ks)*64 + lane
// bytes 131072: gammaP f32[128]; 131584: betaP f32[128]   (total 132096 B)
// Fragment element e (0..7) of (ks): channel c = ks*32 + lg*4 + (e&3) + ((e>>2)<<4)
// ---------------------------------------------------------------------------
__global__ __launch_bounds__(256)
void repack_k(const float* __restrict__ wqkv, const float* __restrict__ wproj,
              const float* __restrict__ gamma, const float* __restrict__ beta,
              unsigned short* __restrict__ ws)
{
    int gid = blockIdx.x * 256 + threadIdx.x;
    uint4* wsq = (uint4*)ws;
    int l = gid & 63, lr = l & 15, lg = (l >> 4) & 3;
    if (gid < 8192) {
        int unit = gid >> 6;
        int col, ks, stride;
        float scale = 1.0f;
        const float* src;
        if (unit < 64) {              // qk A-frags: A[m=col][k=c] = wqkv[c][col]
            int t = unit >> 2; ks = unit & 3;
            int hd = t >> 1, three = t & 1;
            col = three * 128 + hd * 16 + lr;
            src = wqkv; stride = 384;
            if (three == 0) scale = 0.25f;   // fold SCALE into q
        } else if (unit < 96) {       // v B-frags: B[k=c][n] = wqkv[c][256+hd*16+n]
            int u2 = unit - 64; int hd = u2 >> 2; ks = u2 & 3;
            col = 256 + hd * 16 + lr;
            src = wqkv; stride = 384;
        } else {                      // proj B-frags: B[k=c][n] = wproj[c][n]
            int u3 = unit - 96; int nt = u3 >> 2; ks = u3 & 3;
            col = nt * 16 + lr;
            src = wproj; stride = 128;
        }
        unsigned int dw[4];
        #pragma unroll
        for (int i = 0; i < 4; ++i) {
            int e0 = 2 * i, e1 = 2 * i + 1;
            int c0 = ks * 32 + lg * 4 + (e0 & 3) + ((e0 >> 2) << 4);
            int c1 = ks * 32 + lg * 4 + (e1 & 3) + ((e1 >> 2) << 4);
            dw[i] = packbf(src[c0 * stride + col] * scale, src[c1 * stride + col] * scale);
        }
        uint4 o; o.x = dw[0]; o.y = dw[1]; o.z = dw[2]; o.w = dw[3];
        wsq[gid] = o;
    } else if (gid < 8192 + 256) {
        int p = gid - 8192;           // 0..127 gamma, 128..255 beta (permuted)
        int pp = p & 127;
        int ks = pp >> 5, pos = pp & 31;
        int c = ks * 32 + ((pos >> 3) << 2) + (pos & 3) + (((pos >> 2) & 1) << 4);
        ((float*)ws)[32768 + p] = (p < 128) ? gamma[c] : beta[c];
    }
}

// all-register attention for one head, one 64-row group (SCALE pre-folded)
__device__ inline f32x4 attn_ov(f32x4 q, f32x4 k, f32x4 v, bool valid) {
    FragU qb, kb, vb;
    qb.u.x = cvt2(q.x, q.y); qb.u.y = cvt2(q.z, q.w); qb.u.z = 0; qb.u.w = 0;
    kb.u.x = cvt2(k.x, k.y); kb.u.y = cvt2(k.z, k.w); kb.u.z = 0; kb.u.w = 0;
    vb.u.x = cvt2(v.x, v.y); vb.u.y = cvt2(v.z, v.w); vb.u.z = 0; vb.u.w = 0;
    f32x4 zz = {0,0,0,0};
    // S^T = K·Q^T (K=16, upper half zero): lane holds S[q=lr][k=lg*4+j]
    f32x4 st = __builtin_amdgcn_mfma_f32_16x16x32_bf16(kb.v, qb.v, zz, 0, 0, 0);
    float sc0 = st.x, sc1 = st.y, sc2 = st.z, sc3 = st.w;
    float m = valid ? fmaxf(fmaxf(sc0, sc1), fmaxf(sc2, sc3)) : -3.0e38f;
    m = fmaxf(m, __shfl_xor(m, 16));
    float e0 = valid ? __expf(sc0 - m) : 0.f, e1 = valid ? __expf(sc1 - m) : 0.f;
    float e2 = valid ? __expf(sc2 - m) : 0.f, e3 = valid ? __expf(sc3 - m) : 0.f;
    float sm = e0 + e1 + e2 + e3; sm += __shfl_xor(sm, 16);
    float inv = 1.f / sm;
    FragU pb;
    pb.u.x = cvt2(valid ? e0 * inv : 0.f, valid ? e1 * inv : 0.f);
    pb.u.y = cvt2(valid ? e2 * inv : 0.f, valid ? e3 * inv : 0.f);
    pb.u.z = 0; pb.u.w = 0;
    // O^T = V^T·P^T: lane holds O[q=lr][d=lg*4+j]
    return __builtin_amdgcn_mfma_f32_16x16x32_bf16(vb.v, pb.v, zz, 0, 0, 0);
}

// ---------------------------------------------------------------------------
// xln LDS: two 16KB groups (pixels 0-7, 8-15). Within a group, u16 index =
// ks*2048 + row*32 + pos (row = pix_in_group*8 + n; pos = frag permutation of
// c&31) so each lane's MFMA fragment is one aligned ds_read_b128 and a wave
// tiles 1024B regions.
// ---------------------------------------------------------------------------
__global__ __launch_bounds__(256, 3)
void cfa_main(const float* __restrict__ feat, const float* __restrict__ bproj,
              const unsigned short* __restrict__ ws, float* __restrict__ outp)
{
    __shared__ uint4 xlnU4[2048];                    // 32 KB
    unsigned short* xln16 = (unsigned short*)xlnU4;
    unsigned int*   xln32 = (unsigned int*)xlnU4;

    const int tid = threadIdx.x;
    const int blk = (int)(blockIdx.x % NXCD) * CPX + (int)blockIdx.x / NXCD;
    const int wt = blk % 6, h = (blk / 6) % 96, b = blk / (6 * 96);
    const int base = ((b * NFR) * CDIM) * HWSZ + h * WW + wt * 16;

    // ---- phase 1: stage 16 pixels; 4 lanes per (n,c)-row chunk ----
    // Each thread: one channel-PAIR (c even), one pixel quad (pq). The two
    // float4 loads each touch exactly ONE 128B line (16 px = 64B aligned);
    // a wave's load inst covers 16 lines (was 64) -> 4x fewer TA line-slots.
    #pragma unroll
    for (int it = 0; it < 8; ++it) {
        int t = it * 256 + tid;                      // 0..2047
        int pq = t & 3;
        int pr = t >> 2;                             // 0..511 = n*64 + cpair
        int n = pr >> 6;
        int c = (pr & 63) * 2;                       // even channel
        const float* src = feat + base + (n * CDIM + c) * HWSZ + pq * 4;
        float4 f0 = *(const float4*)src;             // ch c,   px pq*4..pq*4+3
        float4 f1 = *(const float4*)(src + HWSZ);    // ch c+1, same pixels
        int ks = c >> 5;
        int pos = posmap(c & 31);                    // even; pos(c+1)=pos+1
        const float* a0 = (const float*)&f0;
        const float* a1 = (const float*)&f1;
        #pragma unroll
        for (int j = 0; j < 4; ++j) {
            int p = pq * 4 + j;
            int g = p >> 3, pin = p & 7;
            xln32[(g * 8192 + ks * 2048 + (pin * 8 + n) * 32 + pos) >> 1] =
                cvt2(a0[j], a1[j]);
        }
    }
    __syncthreads();

    // ---- phase 2: LayerNorm in-place, both groups ----
    {
        const float* gP = (const float*)ws + 32768;
        const float* bP = gP + 128;
        int rr = tid >> 2, ks = tid & 3;
        #pragma unroll
        for (int g = 0; g < 2; ++g) {
            int baseq = g * 1024 + ks * 256 + rr * 4;
            uint4 ch[4];
            #pragma unroll
            for (int j = 0; j < 4; ++j) ch[j] = xlnU4[baseq + ((j + rr + ks) & 3)];
            float s = 0.f, ss = 0.f;
            #pragma unroll
            for (int j = 0; j < 4; ++j) {
                const unsigned short* e = (const unsigned short*)&ch[j];
                #pragma unroll
                for (int b8 = 0; b8 < 8; ++b8) { float x = bf2f(e[b8]); s += x; ss += x * x; }
            }
            s += __shfl_xor(s, 1); ss += __shfl_xor(ss, 1);
            s += __shfl_xor(s, 2); ss += __shfl_xor(ss, 2);
            float mu = s * (1.f / 128.f);
            float var = ss * (1.f / 128.f) - mu * mu;
            float rstd = rsqrtf(var + 1e-5f);
            #pragma unroll
            for (int j = 0; j < 4; ++j) {
                int cj = (j + rr + ks) & 3;
                const unsigned short* e = (const unsigned short*)&ch[j];
                unsigned int dw[4];
                #pragma unroll
                for (int i = 0; i < 4; ++i) {
                    int p0 = cj * 8 + 2 * i, p1 = p0 + 1;
                    float x0 = (bf2f(e[2 * i])     - mu) * rstd * gP[ks * 32 + p0] + bP[ks * 32 + p0];
                    float x1 = (bf2f(e[2 * i + 1]) - mu) * rstd * gP[ks * 32 + p1] + bP[ks * 32 + p1];
                    dw[i] = cvt2(x0, x1);
                }
                uint4 o; o.x = dw[0]; o.y = dw[1]; o.z = dw[2]; o.w = dw[3];
                xlnU4[baseq + cj] = o;
            }
        }
    }
    // no barrier: wave wv LN'd exactly rows [16wv,16wv+16) of BOTH groups and
    // reads only those below (same-wave LDS ops are in-order).

    const int wv = tid >> 6, l = tid & 63, lr = l & 15, lg = l >> 4;
    const uint4* wsq = (const uint4*)ws;

    FragU xf0[4], xf1[4];
    #pragma unroll
    for (int ks = 0; ks < 4; ++ks) {
        xf0[ks].u = xlnU4[ks * 256 + (wv * 16 + lr) * 4 + lg];
        xf1[ks].u = xlnU4[1024 + ks * 256 + (wv * 16 + lr) * 4 + lg];
    }
    __syncthreads();   // all waves have their xf fragments; xlnU4 is now free
                       // for out_t streaming (no xlnU4 reads after this point)

    const bool valid = ((lg >> 1) == (lr >> 3));     // same-pixel (q,k) pairs
    FragU pa0[4], pa1[4];
    #pragma unroll
    for (int ks = 0; ks < 4; ++ks) {
        pa0[ks].u.x = 0; pa0[ks].u.y = 0; pa0[ks].u.z = 0; pa0[ks].u.w = 0;
        pa1[ks].u.x = 0; pa1[ks].u.y = 0; pa1[ks].u.z = 0; pa1[ks].u.w = 0;
    }

    // ---- per-head: weights loaded in-loop (used once each), both groups ----
    #pragma unroll
    for (int hd = 0; hd < 8; ++hd) {
        f32x4 q0 = {0,0,0,0}, k0 = {0,0,0,0}, v0 = {0,0,0,0};
        f32x4 q1 = {0,0,0,0}, k1 = {0,0,0,0}, v1 = {0,0,0,0};
        #pragma unroll
        for (int ks = 0; ks < 4; ++ks) {
            FragU A, B, V2;
            A.u  = wsq[((hd * 2 + 0) * 4 + ks) * 64 + l];
            B.u  = wsq[((hd * 2 + 1) * 4 + ks) * 64 + l];
            V2.u = wsq[4096 + (hd * 4 + ks) * 64 + l];
            q0 = __builtin_amdgcn_mfma_f32_16x16x32_bf16(A.v,  xf0[ks].v, q0, 0, 0, 0);
            k0 = __builtin_amdgcn_mfma_f32_16x16x32_bf16(B.v,  xf0[ks].v, k0, 0, 0, 0);
            q1 = __builtin_amdgcn_mfma_f32_16x16x32_bf16(A.v,  xf1[ks].v, q1, 0, 0, 0);
            k1 = __builtin_amdgcn_mfma_f32_16x16x32_bf16(B.v,  xf1[ks].v, k1, 0, 0, 0);
            v0 = __builtin_amdgcn_mfma_f32_16x16x32_bf16(xf0[ks].v, V2.v, v0, 0, 0, 0);
            v1 = __builtin_amdgcn_mfma_f32_16x16x32_bf16(xf1[ks].v, V2.v, v1, 0, 0, 0);
        }
        f32x4 o0 = attn_ov(q0, k0, v0, valid);
        f32x4 o1 = attn_ov(q1, k1, v1, valid);
        if ((hd & 1) == 0) {
            pa0[hd >> 1].u.x = cvt2(o0.x, o0.y); pa0[hd >> 1].u.y = cvt2(o0.z, o0.w);
            pa1[hd >> 1].u.x = cvt2(o1.x, o1.y); pa1[hd >> 1].u.y = cvt2(o1.z, o1.w);
        } else {
            pa0[hd >> 1].u.z = cvt2(o0.x, o0.y); pa0[hd >> 1].u.w = cvt2(o0.z, o0.w);
            pa1[hd >> 1].u.z = cvt2(o1.x, o1.y); pa1[hd >> 1].u.w = cvt2(o1.z, o1.w);
        }
    }

    // ---- proj GEMM, streamed: per nt compute 2 accs and write to out_t ----
    unsigned short* out_t = xln16;                   // [g][n][col^n][pix]
    #pragma unroll
    for (int nt = 0; nt < 8; ++nt) {
        f32x4 a0 = {0,0,0,0}, a1 = {0,0,0,0};
        #pragma unroll
        for (int ks = 0; ks < 4; ++ks) {
            FragU B; B.u = wsq[6144 + (nt * 4 + ks) * 64 + l];
            a0 = __builtin_amdgcn_mfma_f32_16x16x32_bf16(pa0[ks].v, B.v, a0, 0, 0, 0);
            a1 = __builtin_amdgcn_mfma_f32_16x16x32_bf16(pa1[ks].v, B.v, a1, 0, 0, 0);
        }
        int col = nt * 16 + lr;
        float bias = bproj[col];
        #pragma unroll
        for (int j = 0; j < 4; ++j) {
            int row = wv * 16 + lg * 4 + j;          // row = pix_in_group*8 + n
            int n = row & 7, p = row >> 3;
            out_t[n * 1024 + (col ^ n) * 8 + p]        = cvt1(a0[j] + bias);
            out_t[8192 + n * 1024 + (col ^ n) * 8 + p] = cvt1(a1[j] + bias);
        }
    }
    __syncthreads();
    // ---- epilogue: residual + store; 4 lanes per (n,c)-row (1 line/quad) ----
    #pragma unroll 4
    for (int it = 0; it < 16; ++it) {
        int t = it * 256 + tid;                      // 0..4095
        int pq = t & 3;
        int row = t >> 2;                            // 0..1023 = n*128 + c
        int n = row >> 7, c = row & 127;
        int gaddr = base + (n * CDIM + c) * HWSZ + pq * 4;
        float4 r0 = *(const float4*)(feat + gaddr);
        int p = pq * 4;
        int idx = (p >> 3) * 8192 + n * 1024 + (c ^ n) * 8 + (p & 7);
        uint2 tv = *(const uint2*)(out_t + idx);     // 4 consecutive pixels
        const unsigned short* tp = (const unsigned short*)&tv;
        float4 o;
        o.x = r0.x + bf2f(tp[0]); o.y = r0.y + bf2f(tp[1]);
        o.z = r0.z + bf2f(tp[2]); o.w = r0.w + bf2f(tp[3]);
        *(float4*)(outp + gaddr) = o;
    }
}

extern "C" void kernel_launch(void* const* d_in, const int* in_sizes, int n_in,
                              void* d_out, int out_size, void* d_ws, size_t ws_size,
                              hipStream_t stream) {
    const float* feat  = (const float*)d_in[0];
    const float* wqkv  = (const float*)d_in[1];
    const float* wproj = (const float*)d_in[2];
    const float* bproj = (const float*)d_in[3];
    const float* gamma = (const float*)d_in[4];
    const float* beta  = (const float*)d_in[5];
    unsigned short* ws = (unsigned short*)d_ws;      // needs 132096 B
    float* outp = (float*)d_out;

    hipLaunchKernelGGL(repack_k, dim3(33), dim3(256), 0, stream,
                       wqkv, wproj, gamma, beta, ws);
    hipLaunchKernelGGL(cfa_main, dim3(NBLK), dim3(256), 0, stream,
                       feat, bproj, ws, outp);
}

// Round 11
// 114.631 us; speedup vs baseline: 3.6850x; 1.1172x over previous
//
#include <hip/hip_runtime.h>

#define NFR 8
#define CDIM 128
#define HH 96
#define WW 96
#define NB 4
#define HWSZ 9216        // HH*WW
#define NBLK 2304        // NB*HH*(WW/16)
#define NXCD 8
#define CPX (NBLK / NXCD)  // 288

typedef __attribute__((ext_vector_type(8))) short bf16x8;
typedef __attribute__((ext_vector_type(4))) float f32x4;
typedef __attribute__((ext_vector_type(2))) float f32x2;
typedef __attribute__((ext_vector_type(2))) __bf16 bf16x2;

union FragU { uint4 u; bf16x8 v; };

__device__ inline float bf2f(unsigned short h) {
    unsigned int x = ((unsigned int)h) << 16;
    float f; __builtin_memcpy(&f, &x, 4); return f;
}
__device__ inline unsigned short f2bf(float f) {
    unsigned int x; __builtin_memcpy(&x, &f, 4);
    return (unsigned short)((x + 0x7FFFu + ((x >> 16) & 1u)) >> 16);
}
__device__ inline unsigned int packbf(float a, float b) {
    return (unsigned int)f2bf(a) | ((unsigned int)f2bf(b) << 16);
}
// HW path: compiler emits v_cvt_pk_bf16_f32 (RNE, same results as packbf)
__device__ inline unsigned int cvt2(float a, float b) {
    f32x2 f = {a, b};
    bf16x2 h = __builtin_convertvector(f, bf16x2);
    unsigned int u; __builtin_memcpy(&u, &h, 4); return u;
}
__device__ inline unsigned short cvt1(float a) {
    __bf16 h = (__bf16)a;
    unsigned short s; __builtin_memcpy(&s, &h, 2); return s;
}
// fragment-permutation position of channel-within-32 (even for even c5)
__device__ inline int posmap(int c5) {
    return (c5 < 16) ? (((c5 >> 2) << 3) + (c5 & 3))
                     : ((((c5 & 15) >> 2) << 3) + 4 + (c5 & 3));
}

// ---------------------------------------------------------------------------
// ws layout (uint4 units of 16B):
//   [0,    4096) : qk A-frags   ((hd*2+three)*4+ks)*64 + lane   (three: 0=q,1=k)
//                  q fragments pre-scaled by 0.25 (attention SCALE folded in)
//   [4096, 6144) : v  B-frags   (hd*4+ks)*64 + lane
//   [6144, 8192) : proj B-frags (nt*4+ks)*64 + lane
// bytes 131072: gammaP f32[128]; 131584: betaP f32[128]   (total 132096 B)
// Fragment element e (0..7) of (ks): channel c = ks*32 + lg*4 + (e&3) + ((e>>2)<<4)
// ---------------------------------------------------------------------------
__global__ __launch_bounds__(256)
void repack_k(const float* __restrict__ wqkv, const float* __restrict__ wproj,
              const float* __restrict__ gamma, const float* __restrict__ beta,
              unsigned short* __restrict__ ws)
{
    int gid = blockIdx.x * 256 + threadIdx.x;
    uint4* wsq = (uint4*)ws;
    int l = gid & 63, lr = l & 15, lg = (l >> 4) & 3;
    if (gid < 8192) {
        int unit = gid >> 6;
        int col, ks, stride;
        float scale = 1.0f;
        const float* src;
        if (unit < 64) {              // qk A-frags: A[m=col][k=c] = wqkv[c][col]
            int t = unit >> 2; ks = unit & 3;
            int hd = t >> 1, three = t & 1;
            col = three * 128 + hd * 16 + lr;
            src = wqkv; stride = 384;
            if (three == 0) scale = 0.25f;   // fold SCALE into q
        } else if (unit < 96) {       // v B-frags: B[k=c][n] = wqkv[c][256+hd*16+n]
            int u2 = unit - 64; int hd = u2 >> 2; ks = u2 & 3;
            col = 256 + hd * 16 + lr;
            src = wqkv; stride = 384;
        } else {                      // proj B-frags: B[k=c][n] = wproj[c][n]
            int u3 = unit - 96; int nt = u3 >> 2; ks = u3 & 3;
            col = nt * 16 + lr;
            src = wproj; stride = 128;
        }
        unsigned int dw[4];
        #pragma unroll
        for (int i = 0; i < 4; ++i) {
            int e0 = 2 * i, e1 = 2 * i + 1;
            int c0 = ks * 32 + lg * 4 + (e0 & 3) + ((e0 >> 2) << 4);
            int c1 = ks * 32 + lg * 4 + (e1 & 3) + ((e1 >> 2) << 4);
            dw[i] = packbf(src[c0 * stride + col] * scale, src[c1 * stride + col] * scale);
        }
        uint4 o; o.x = dw[0]; o.y = dw[1]; o.z = dw[2]; o.w = dw[3];
        wsq[gid] = o;
    } else if (gid < 8192 + 256) {
        int p = gid - 8192;           // 0..127 gamma, 128..255 beta (permuted)
        int pp = p & 127;
        int ks = pp >> 5, pos = pp & 31;
        int c = ks * 32 + ((pos >> 3) << 2) + (pos & 3) + (((pos >> 2) & 1) << 4);
        ((float*)ws)[32768 + p] = (p < 128) ? gamma[c] : beta[c];
    }
}

// all-register attention for one head, one 64-row group (SCALE pre-folded)
__device__ inline f32x4 attn_ov(f32x4 q, f32x4 k, f32x4 v, bool valid) {
    FragU qb, kb, vb;
    qb.u.x = cvt2(q.x, q.y); qb.u.y = cvt2(q.z, q.w); qb.u.z = 0; qb.u.w = 0;
    kb.u.x = cvt2(k.x, k.y); kb.u.y = cvt2(k.z, k.w); kb.u.z = 0; kb.u.w = 0;
    vb.u.x = cvt2(v.x, v.y); vb.u.y = cvt2(v.z, v.w); vb.u.z = 0; vb.u.w = 0;
    f32x4 zz = {0,0,0,0};
    // S^T = K·Q^T (K=16, upper half zero): lane holds S[q=lr][k=lg*4+j]
    f32x4 st = __builtin_amdgcn_mfma_f32_16x16x32_bf16(kb.v, qb.v, zz, 0, 0, 0);
    float sc0 = st.x, sc1 = st.y, sc2 = st.z, sc3 = st.w;
    float m = valid ? fmaxf(fmaxf(sc0, sc1), fmaxf(sc2, sc3)) : -3.0e38f;
    m = fmaxf(m, __shfl_xor(m, 16));
    float e0 = valid ? __expf(sc0 - m) : 0.f, e1 = valid ? __expf(sc1 - m) : 0.f;
    float e2 = valid ? __expf(sc2 - m) : 0.f, e3 = valid ? __expf(sc3 - m) : 0.f;
    float sm = e0 + e1 + e2 + e3; sm += __shfl_xor(sm, 16);
    float inv = 1.f / sm;
    FragU pb;
    pb.u.x = cvt2(valid ? e0 * inv : 0.f, valid ? e1 * inv : 0.f);
    pb.u.y = cvt2(valid ? e2 * inv : 0.f, valid ? e3 * inv : 0.f);
    pb.u.z = 0; pb.u.w = 0;
    // O^T = V^T·P^T: lane holds O[q=lr][d=lg*4+j]
    return __builtin_amdgcn_mfma_f32_16x16x32_bf16(vb.v, pb.v, zz, 0, 0, 0);
}

// ---------------------------------------------------------------------------
// xln LDS: two 16KB groups (pixels 0-7, 8-15). Within a group, u16 index =
// ks*2048 + row*32 + pos (row = pix_in_group*8 + n; pos = frag permutation of
// c&31) so each lane's MFMA fragment is one aligned ds_read_b128 and a wave
// tiles 1024B regions.
// ---------------------------------------------------------------------------
__global__ __launch_bounds__(256, 3)
void cfa_main(const float* __restrict__ feat, const float* __restrict__ bproj,
              const unsigned short* __restrict__ ws, float* __restrict__ outp)
{
    __shared__ uint4 xlnU4[2048];                    // 32 KB
    unsigned short* xln16 = (unsigned short*)xlnU4;
    unsigned int*   xln32 = (unsigned int*)xlnU4;

    const int tid = threadIdx.x;
    const int blk = (int)(blockIdx.x % NXCD) * CPX + (int)blockIdx.x / NXCD;
    const int wt = blk % 6, h = (blk / 6) % 96, b = blk / (6 * 96);
    const int base = ((b * NFR) * CDIM) * HWSZ + h * WW + wt * 16;

    // ---- phase 1: stage 16 pixels; 4 lanes per (n,c)-row chunk ----
    #pragma unroll
    for (int it = 0; it < 8; ++it) {
        int t = it * 256 + tid;                      // 0..2047
        int pq = t & 3;
        int pr = t >> 2;                             // 0..511 = n*64 + cpair
        int n = pr >> 6;
        int c = (pr & 63) * 2;                       // even channel
        const float* src = feat + base + (n * CDIM + c) * HWSZ + pq * 4;
        float4 f0 = *(const float4*)src;             // ch c,   px pq*4..pq*4+3
        float4 f1 = *(const float4*)(src + HWSZ);    // ch c+1, same pixels
        int ks = c >> 5;
        int pos = posmap(c & 31);                    // even; pos(c+1)=pos+1
        const float* a0 = (const float*)&f0;
        const float* a1 = (const float*)&f1;
        #pragma unroll
        for (int j = 0; j < 4; ++j) {
            int p = pq * 4 + j;
            int g = p >> 3, pin = p & 7;
            xln32[(g * 8192 + ks * 2048 + (pin * 8 + n) * 32 + pos) >> 1] =
                cvt2(a0[j], a1[j]);
        }
    }
    __syncthreads();

    const int wv = tid >> 6, l = tid & 63, lr = l & 15, lg = l >> 4;
    const uint4* wsq = (const uint4*)ws;

    // ---- prefetch head-0 weights NOW: L2 latency hides under LayerNorm ----
    uint4 Ac[4], Bc[4], Vc[4];
    #pragma unroll
    for (int ks = 0; ks < 4; ++ks) {
        Ac[ks] = wsq[(0 * 8 + ks) * 64 + l];
        Bc[ks] = wsq[(0 * 8 + 4 + ks) * 64 + l];
        Vc[ks] = wsq[4096 + ks * 64 + l];
    }

    // ---- phase 2: LayerNorm in-place, both groups ----
    {
        const float* gP = (const float*)ws + 32768;
        const float* bP = gP + 128;
        int rr = tid >> 2, ks = tid & 3;
        #pragma unroll
        for (int g = 0; g < 2; ++g) {
            int baseq = g * 1024 + ks * 256 + rr * 4;
            uint4 ch[4];
            #pragma unroll
            for (int j = 0; j < 4; ++j) ch[j] = xlnU4[baseq + ((j + rr + ks) & 3)];
            float s = 0.f, ss = 0.f;
            #pragma unroll
            for (int j = 0; j < 4; ++j) {
                const unsigned short* e = (const unsigned short*)&ch[j];
                #pragma unroll
                for (int b8 = 0; b8 < 8; ++b8) { float x = bf2f(e[b8]); s += x; ss += x * x; }
            }
            s += __shfl_xor(s, 1); ss += __shfl_xor(ss, 1);
            s += __shfl_xor(s, 2); ss += __shfl_xor(ss, 2);
            float mu = s * (1.f / 128.f);
            float var = ss * (1.f / 128.f) - mu * mu;
            float rstd = rsqrtf(var + 1e-5f);
            #pragma unroll
            for (int j = 0; j < 4; ++j) {
                int cj = (j + rr + ks) & 3;
                const unsigned short* e = (const unsigned short*)&ch[j];
                unsigned int dw[4];
                #pragma unroll
                for (int i = 0; i < 4; ++i) {
                    int p0 = cj * 8 + 2 * i, p1 = p0 + 1;
                    float x0 = (bf2f(e[2 * i])     - mu) * rstd * gP[ks * 32 + p0] + bP[ks * 32 + p0];
                    float x1 = (bf2f(e[2 * i + 1]) - mu) * rstd * gP[ks * 32 + p1] + bP[ks * 32 + p1];
                    dw[i] = cvt2(x0, x1);
                }
                uint4 o; o.x = dw[0]; o.y = dw[1]; o.z = dw[2]; o.w = dw[3];
                xlnU4[baseq + cj] = o;
            }
        }
    }
    // no barrier: wave wv LN'd exactly rows [16wv,16wv+16) of BOTH groups and
    // reads only those below (same-wave LDS ops are in-order).

    FragU xf0[4], xf1[4];
    #pragma unroll
    for (int ks = 0; ks < 4; ++ks) {
        xf0[ks].u = xlnU4[ks * 256 + (wv * 16 + lr) * 4 + lg];
        xf1[ks].u = xlnU4[1024 + ks * 256 + (wv * 16 + lr) * 4 + lg];
    }
    __syncthreads();   // all waves have their xf fragments; xlnU4 is now free
                       // for out_t streaming (no xlnU4 reads after this point)

    const bool valid = ((lg >> 1) == (lr >> 3));     // same-pixel (q,k) pairs
    FragU pa0[4], pa1[4];
    #pragma unroll
    for (int ks = 0; ks < 4; ++ks) {
        pa0[ks].u.x = 0; pa0[ks].u.y = 0; pa0[ks].u.z = 0; pa0[ks].u.w = 0;
        pa1[ks].u.x = 0; pa1[ks].u.y = 0; pa1[ks].u.z = 0; pa1[ks].u.w = 0;
    }

    // ---- per-head loop, software-pipelined depth 2 (issue hd+1, use hd) ----
    uint4 PBc[4];                                    // proj nt=0 frags (loaded @hd=7)
    float biasc;
    #pragma unroll
    for (int hd = 0; hd < 8; ++hd) {
        uint4 An[4], Bn[4], Vn[4];
        if (hd < 7) {
            #pragma unroll
            for (int ks = 0; ks < 4; ++ks) {
                An[ks] = wsq[((hd + 1) * 8 + ks) * 64 + l];
                Bn[ks] = wsq[((hd + 1) * 8 + 4 + ks) * 64 + l];
                Vn[ks] = wsq[4096 + ((hd + 1) * 4 + ks) * 64 + l];
            }
        } else {
            #pragma unroll
            for (int ks = 0; ks < 4; ++ks) PBc[ks] = wsq[6144 + ks * 64 + l];
            biasc = bproj[lr];                       // nt=0: col = lr
        }
        f32x4 q0 = {0,0,0,0}, k0 = {0,0,0,0}, v0 = {0,0,0,0};
        f32x4 q1 = {0,0,0,0}, k1 = {0,0,0,0}, v1 = {0,0,0,0};
        #pragma unroll
        for (int ks = 0; ks < 4; ++ks) {
            FragU A, B, V2; A.u = Ac[ks]; B.u = Bc[ks]; V2.u = Vc[ks];
            q0 = __builtin_amdgcn_mfma_f32_16x16x32_bf16(A.v,  xf0[ks].v, q0, 0, 0, 0);
            k0 = __builtin_amdgcn_mfma_f32_16x16x32_bf16(B.v,  xf0[ks].v, k0, 0, 0, 0);
            q1 = __builtin_amdgcn_mfma_f32_16x16x32_bf16(A.v,  xf1[ks].v, q1, 0, 0, 0);
            k1 = __builtin_amdgcn_mfma_f32_16x16x32_bf16(B.v,  xf1[ks].v, k1, 0, 0, 0);
            v0 = __builtin_amdgcn_mfma_f32_16x16x32_bf16(xf0[ks].v, V2.v, v0, 0, 0, 0);
            v1 = __builtin_amdgcn_mfma_f32_16x16x32_bf16(xf1[ks].v, V2.v, v1, 0, 0, 0);
        }
        f32x4 o0 = attn_ov(q0, k0, v0, valid);
        f32x4 o1 = attn_ov(q1, k1, v1, valid);
        if ((hd & 1) == 0) {
            pa0[hd >> 1].u.x = cvt2(o0.x, o0.y); pa0[hd >> 1].u.y = cvt2(o0.z, o0.w);
            pa1[hd >> 1].u.x = cvt2(o1.x, o1.y); pa1[hd >> 1].u.y = cvt2(o1.z, o1.w);
        } else {
            pa0[hd >> 1].u.z = cvt2(o0.x, o0.y); pa0[hd >> 1].u.w = cvt2(o0.z, o0.w);
            pa1[hd >> 1].u.z = cvt2(o1.x, o1.y); pa1[hd >> 1].u.w = cvt2(o1.z, o1.w);
        }
        if (hd < 7) {
            #pragma unroll
            for (int ks = 0; ks < 4; ++ks) { Ac[ks] = An[ks]; Bc[ks] = Bn[ks]; Vc[ks] = Vn[ks]; }
        }
    }

    // ---- proj GEMM, streamed + prefetched: per nt compute 2 accs -> out_t ----
    unsigned short* out_t = xln16;                   // [g][n][col^n][pix]
    #pragma unroll
    for (int nt = 0; nt < 8; ++nt) {
        uint4 PBn[4]; float biasn;
        if (nt < 7) {
            #pragma unroll
            for (int ks = 0; ks < 4; ++ks) PBn[ks] = wsq[6144 + ((nt + 1) * 4 + ks) * 64 + l];
            biasn = bproj[(nt + 1) * 16 + lr];
        }
        f32x4 a0 = {0,0,0,0}, a1 = {0,0,0,0};
        #pragma unroll
        for (int ks = 0; ks < 4; ++ks) {
            FragU B; B.u = PBc[ks];
            a0 = __builtin_amdgcn_mfma_f32_16x16x32_bf16(pa0[ks].v, B.v, a0, 0, 0, 0);
            a1 = __builtin_amdgcn_mfma_f32_16x16x32_bf16(pa1[ks].v, B.v, a1, 0, 0, 0);
        }
        int col = nt * 16 + lr;
        #pragma unroll
        for (int j = 0; j < 4; ++j) {
            int row = wv * 16 + lg * 4 + j;          // row = pix_in_group*8 + n
            int n = row & 7, p = row >> 3;
            out_t[n * 1024 + (col ^ n) * 8 + p]        = cvt1(a0[j] + biasc);
            out_t[8192 + n * 1024 + (col ^ n) * 8 + p] = cvt1(a1[j] + biasc);
        }
        if (nt < 7) {
            #pragma unroll
            for (int ks = 0; ks < 4; ++ks) PBc[ks] = PBn[ks];
            biasc = biasn;
        }
    }
    __syncthreads();
    // ---- epilogue: residual + store; 4 lanes per (n,c)-row (1 line/quad) ----
    #pragma unroll 4
    for (int it = 0; it < 16; ++it) {
        int t = it * 256 + tid;                      // 0..4095
        int pq = t & 3;
        int row = t >> 2;                            // 0..1023 = n*128 + c
        int n = row >> 7, c = row & 127;
        int gaddr = base + (n * CDIM + c) * HWSZ + pq * 4;
        float4 r0 = *(const float4*)(feat + gaddr);
        int p = pq * 4;
        int idx = (p >> 3) * 8192 + n * 1024 + (c ^ n) * 8 + (p & 7);
        uint2 tv = *(const uint2*)(out_t + idx);     // 4 consecutive pixels
        const unsigned short* tp = (const unsigned short*)&tv;
        float4 o;
        o.x = r0.x + bf2f(tp[0]); o.y = r0.y + bf2f(tp[1]);
        o.z = r0.z + bf2f(tp[2]); o.w = r0.w + bf2f(tp[3]);
        *(float4*)(outp + gaddr) = o;
    }
}

extern "C" void kernel_launch(void* const* d_in, const int* in_sizes, int n_in,
                              void* d_out, int out_size, void* d_ws, size_t ws_size,
                              hipStream_t stream) {
    const float* feat  = (const float*)d_in[0];
    const float* wqkv  = (const float*)d_in[1];
    const float* wproj = (const float*)d_in[2];
    const float* bproj = (const float*)d_in[3];
    const float* gamma = (const float*)d_in[4];
    const float* beta  = (const float*)d_in[5];
    unsigned short* ws = (unsigned short*)d_ws;      // needs 132096 B
    float* outp = (float*)d_out;

    hipLaunchKernelGGL(repack_k, dim3(33), dim3(256), 0, stream,
                       wqkv, wproj, gamma, beta, ws);
    hipLaunchKernelGGL(cfa_main, dim3(NBLK), dim3(256), 0, stream,
                       feat, bproj, ws, outp);
}